// Round 4
// baseline (508.680 us; speedup 1.0000x reference)
//
#include <hip/hip_runtime.h>
#include <stdint.h>

#define BATCH 65536
#define FDIM 512
#define HDIM 256
#define NC 10
#define NREP 16

typedef short short8 __attribute__((ext_vector_type(8)));
typedef float f32x4 __attribute__((ext_vector_type(4)));

// ---- workspace layout (bytes) ----
// Fragment-tiled layout: tile (I=row/16, C=k/32) is 1KB at (I*nC + C)*1024;
// slot l = (row&15) | (((k>>3)&3)<<4) holds 8 bf16 (k = (l>>4)*8 .. +7).
#define OFF_FC0T   ((size_t)0)                          // 32 J x 16 C tiles
#define OFF_FC1T   (OFF_FC0T + (size_t)512*512*2)
#define OFF_WT     (OFF_FC1T + (size_t)512*512*2)       // 16 J x 16 C tiles
#define OFF_XT     (OFF_WT   + (size_t)256*512*2)       // 4096 I x 16 C (64MB)
#define OFF_X4T    (OFF_XT   + (size_t)BATCH*512*2)     // 4096 I x 16 C (64MB)
#define OFF_ACC    (OFF_X4T  + (size_t)BATCH*512*2)
#define SCAL_SUMSQ 0
#define SCAL_CE    16
#define SCAL_ACC   32
#define SCAL_L1    48
#define SCAL_CTR   64                     // completion counter (int)
#define SCAL_N     128
#define CNT_OFF    SCAL_N                 // NREP*16 floats
#define GSUM_OFF   (SCAL_N + NREP*16)     // NREP*5120 floats
#define ACC_FLOATS (GSUM_OFF + NREP*5120) // 82304 floats
#define OFF_W1T    (OFF_ACC + (size_t)ACC_FLOATS*4)     // 8 C-tiles x 1KB (w1 bf16, padded to 16 classes)

#define GLL(g,l) __builtin_amdgcn_global_load_lds((const __attribute__((address_space(1))) void*)(g), (__attribute__((address_space(3))) void*)(l), 16, 0, 0)

__device__ __forceinline__ unsigned short f2b(float f){
  unsigned u = __float_as_uint(f);
  u += 0x7FFFu + ((u >> 16) & 1u);
  return (unsigned short)(u >> 16);
}
__device__ __forceinline__ float b2f(unsigned short h){
  return __uint_as_float(((unsigned)h) << 16);
}
__device__ __forceinline__ unsigned pk2b(float f0, float f1){
  unsigned u0 = __float_as_uint(f0) + 0x8000u;
  unsigned u1 = __float_as_uint(f1) + 0x8000u;
  return __builtin_amdgcn_perm(u1, u0, 0x07060302u);
}
__device__ __forceinline__ float ald(const float* p){
  return __hip_atomic_load(p, __ATOMIC_RELAXED, __HIP_MEMORY_SCOPE_AGENT);
}

// ---- K0: setup — xcast (0..1023), weight prep (1024..1359), zero (1360..1440),
//      class counts (1441..1456; private slots, no zero dependency)
__global__ __launch_bounds__(256) void k_setup(
    const float* __restrict__ x,   const float* __restrict__ fc0,
    const float* __restrict__ fc1, const float* __restrict__ w,
    const float* __restrict__ w1,  const int* __restrict__ y,
    unsigned short* __restrict__ xT,   unsigned short* __restrict__ fc0T,
    unsigned short* __restrict__ fc1T, unsigned short* __restrict__ wT,
    unsigned short* __restrict__ w1T,  float* __restrict__ accb)
{
  int blk = blockIdx.x, t = threadIdx.x;
  if (blk < 1024){
    int I = blk*4 + (t >> 6);
    int l = t & 63;
    int row = I*16 + (l & 15), q = l >> 4;
    const float* src = x + (size_t)row*FDIM + q*8;
    #pragma unroll
    for (int C = 0; C < 16; ++C){
      float4 v0 = *(const float4*)(src + C*32);
      float4 v1 = *(const float4*)(src + C*32 + 4);
      unsigned o[4];
      o[0] = pk2b(v0.x, v0.y); o[1] = pk2b(v0.z, v0.w);
      o[2] = pk2b(v1.x, v1.y); o[3] = pk2b(v1.z, v1.w);
      *(short8*)&xT[(((size_t)I*16 + C) << 9) + l*8] = *(short8*)o;
    }
    return;
  }
  if (blk < 1360){
    int i = (blk - 1024)*256 + t;
    float l1v = 0.f;
    if (i < 32768){                       // fc0 [k][512] -> tiled
      int n4 = i&15, m = (i>>4)&3, C = (i>>6)&15, J = i>>10;
      int n = J*16+n4, k8 = C*4+m;
      unsigned short o[8];
      #pragma unroll
      for (int j=0;j<8;++j){ float v = fc0[(size_t)(k8*8+j)*512 + n]; o[j]=f2b(v); l1v += fabsf(v); }
      *(short8*)&fc0T[(size_t)(J*16+C)*512 + (i&63)*8] = *(short8*)o;
    } else if (i < 65536){                // fc1
      int j0 = i - 32768;
      int n4 = j0&15, m = (j0>>4)&3, C = (j0>>6)&15, J = j0>>10;
      int n = J*16+n4, k8 = C*4+m;
      unsigned short o[8];
      #pragma unroll
      for (int j=0;j<8;++j){ float v = fc1[(size_t)(k8*8+j)*512 + n]; o[j]=f2b(v); l1v += fabsf(v); }
      *(short8*)&fc1T[(size_t)(J*16+C)*512 + (j0&63)*8] = *(short8*)o;
    } else if (i < 81920){                // w [k][256]
      int j0 = i - 65536;
      int n4 = j0&15, m = (j0>>4)&3, C = (j0>>6)&15, J = j0>>10;
      int n = J*16+n4, k8 = C*4+m;
      unsigned short o[8];
      #pragma unroll
      for (int j=0;j<8;++j){ float v = w[(size_t)(k8*8+j)*256 + n]; o[j]=f2b(v); l1v += fabsf(v); }
      *(short8*)&wT[(size_t)(J*16+C)*512 + (j0&63)*8] = *(short8*)o;
    } else if (i < 86016){                // w1 -> B-fragment tiles (16 classes padded), + L1
      int j0 = i - 81920;                 // 0..4095, one bf16 each
      int C = j0 >> 9, l = (j0 >> 3) & 63, e = j0 & 7;
      int n = l & 15, k = C*32 + (l>>4)*8 + e;
      float v = (n < NC) ? w1[k*NC + n] : 0.f;
      w1T[C*512 + l*8 + e] = f2b(v);
      if (n < NC) l1v = fabsf(v);
    }
    for (int off = 32; off; off >>= 1) l1v += __shfl_down(l1v, off);
    if ((t & 63) == 0 && l1v != 0.f)
      atomicAdd(&accb[SCAL_L1 + (blk & (NREP-1))], l1v);
    return;
  }
  if (blk < 1441){
    int base = (blk - 1360)*1024;
    #pragma unroll
    for (int j=0;j<4;++j){
      int idx = base + j*256 + t;
      // exclude CNT region [CNT_OFF, CNT_OFF+256): fully written by cnt blocks
      if (idx < ACC_FLOATS && (idx < CNT_OFF || idx >= CNT_OFF + NREP*16))
        accb[idx] = 0.f;
    }
    return;
  }
  {
    // class counts: 16 blocks, 4096 labels each, private gcnt slot
    __shared__ float cntS[16];
    int b = blk - 1441;
    if (t < 16) cntS[t] = 0.f;
    __syncthreads();
    int base = b*4096;
    for (int i = t; i < 4096; i += 256) atomicAdd(&cntS[y[base+i]], 1.f);
    __syncthreads();
    if (t < 16) accb[CNT_OFF + b*16 + t] = cntS[t];
  }
}

// ---------------------------------------------------------------------------
// 8-phase fine-interleaved K-loop (round-3 verified; neutral vs 2-phase but
// kept). Block = 256 rows x (128 cols x 2 matrices); 8 waves; BK=64;
// double-buffered 128KB LDS (per buffer: A 32KB @0, B0 16KB @32K, B1 16KB @48K).
// ---------------------------------------------------------------------------

#define BARRIER() __builtin_amdgcn_s_barrier()
#define LGKM0() do{ asm volatile("s_waitcnt lgkmcnt(0)" ::: "memory"); \
                    __builtin_amdgcn_sched_barrier(0); }while(0)

#define RA(AB, C) do{                                                         \
  _Pragma("unroll") for (int m_=0;m_<8;++m_)                                  \
    a[m_] = *(const short8*)((AB) + (((wr*8+m_)*2 + (C))<<10) + lane*16);     \
}while(0)

#define RB(AB, MAT, C) do{                                                    \
  _Pragma("unroll") for (int n_=0;n_<2;++n_)                                  \
    bb[n_] = *(const short8*)((AB) + 32768 + (MAT)*16384 +                    \
                              (((wc*2+n_)*2 + (C))<<10) + lane*16);           \
}while(0)

#define MM16(ACC) do{                                                         \
  __builtin_amdgcn_s_setprio(1);                                              \
  _Pragma("unroll") for (int n_=0;n_<2;++n_)                                  \
  _Pragma("unroll") for (int m_=0;m_<8;++m_)                                  \
    ACC[m_][n_] = __builtin_amdgcn_mfma_f32_16x16x32_bf16(a[m_], bb[n_], ACC[m_][n_], 0,0,0); \
  __builtin_amdgcn_s_setprio(0);                                              \
}while(0)

#define SA(KT, C) do{                                                         \
  char* d_ = ldsd + (((KT)&1) ? 65536 : 0);                                   \
  _Pragma("unroll") for (int r_=0;r_<2;++r_){                                 \
    int I_ = wv + r_*8;                                                       \
    GLL(xb + (((size_t)((rowblk*16 + I_)*16 + (KT)*2 + (C))) << 10) + lane*16,\
        d_ + ((I_*2 + (C)) << 10) + lane*16);                                 \
  } }while(0)

#define SB(KT, C) do{                                                         \
  char* d_ = ldsd + (((KT)&1) ? 65536 : 0) + 32768;                           \
  GLL(b0b + (((size_t)((colblk*8 + wv)*16 + (KT)*2 + (C))) << 10) + lane*16,  \
      d_ + ((wv*2 + (C)) << 10) + lane*16);                                   \
  GLL(b1b + (((size_t)((colblk*8 + wv)*16 + (KT)*2 + (C))) << 10) + lane*16,  \
      d_ + 16384 + ((wv*2 + (C)) << 10) + lane*16);                           \
}while(0)

#define KLOOP() do{                                                           \
  SA(0,0); SB(0,0); SA(0,1); SB(0,1); SA(1,0); SB(1,0); SA(1,1);              \
  asm volatile("s_waitcnt vmcnt(6)" ::: "memory");                            \
  __builtin_amdgcn_sched_barrier(0);                                          \
  BARRIER();                                                                  \
  _Pragma("unroll")                                                           \
  for (int i = 0; i < 4; ++i){                                                \
    int kt0 = 2*i, kt1 = 2*i+1;                                               \
    char* Ab0 = ldsd + ((kt0 & 1) ? 65536 : 0);                               \
    char* Ab1 = ldsd + ((kt1 & 1) ? 65536 : 0);                               \
    RA(Ab0, 0); RB(Ab0, 0, 0);                                                \
    SB(kt1, 1);                                                               \
    BARRIER(); LGKM0(); MM16(acc1);                                           \
    BARRIER();                                                                \
    RB(Ab0, 1, 0);                                                            \
    if (i < 3) SA(kt0+2, 0);                                                  \
    BARRIER(); LGKM0(); MM16(acc2);                                           \
    BARRIER();                                                                \
    RA(Ab0, 1); RB(Ab0, 0, 1);                                                \
    if (i < 3) SB(kt0+2, 0);                                                  \
    BARRIER(); LGKM0(); MM16(acc1);                                           \
    BARRIER();                                                                \
    RB(Ab0, 1, 1);                                                            \
    if (i < 3) SA(kt0+2, 1);                                                  \
    BARRIER(); LGKM0(); MM16(acc2);                                           \
    if (i < 3) { asm volatile("s_waitcnt vmcnt(6)" ::: "memory"); }           \
    else       { asm volatile("s_waitcnt vmcnt(0)" ::: "memory"); }           \
    __builtin_amdgcn_sched_barrier(0);                                        \
    BARRIER();                                                                \
    RA(Ab1, 0); RB(Ab1, 0, 0);                                                \
    if (i < 3) SB(kt0+2, 1);                                                  \
    BARRIER(); LGKM0(); MM16(acc1);                                           \
    BARRIER();                                                                \
    RB(Ab1, 1, 0);                                                            \
    if (i < 3) SA(kt1+2, 0);                                                  \
    BARRIER(); LGKM0(); MM16(acc2);                                           \
    BARRIER();                                                                \
    RA(Ab1, 1); RB(Ab1, 0, 1);                                                \
    if (i < 3) SB(kt1+2, 0);                                                  \
    BARRIER(); LGKM0(); MM16(acc1);                                           \
    BARRIER();                                                                \
    RB(Ab1, 1, 1);                                                            \
    if (i < 3) SA(kt1+2, 1);                                                  \
    BARRIER(); LGKM0(); MM16(acc2);                                           \
    if (i < 3) { asm volatile("s_waitcnt vmcnt(6)" ::: "memory");             \
                 __builtin_amdgcn_sched_barrier(0); }                         \
    BARRIER();                                                                \
  }                                                                           \
}while(0)

// K1: dual GEMM x@fc0, x@fc1 + gated residual + FUSED class-sum (ex-k_csum).
__global__ __launch_bounds__(512, 2) void k_gemm12(
    const unsigned short* __restrict__ xT,
    const unsigned short* __restrict__ fc0T,
    const unsigned short* __restrict__ fc1T,
    const int* __restrict__ y,
    unsigned short* __restrict__ x4T,
    float* __restrict__ accb)
{
  extern __shared__ __align__(16) char ldsd[];   // 131072 dynamic
  float* scal = accb;
  float* gsum = accb + GSUM_OFF;

  int blk = blockIdx.x;
  int wg = (blk & 7)*128 + (blk >> 3);           // bijective XCD chunking (1024%8==0)
  int rowblk = wg >> 2;                          // 0..255 (256 rows each)
  int colblk = wg & 3;                           // 0..3   (128 cols each)

  int t = threadIdx.x;
  int wv = t >> 6, lane = t & 63, ln = lane & 15, quad = lane >> 4;
  int wr = wv >> 2, wc = wv & 3;                 // 2 x 4 wave grid

  const char* xb  = (const char*)xT;
  const char* b0b = (const char*)fc0T;
  const char* b1b = (const char*)fc1T;

  const f32x4 zv = {0.f,0.f,0.f,0.f};
  f32x4 acc1[8][2], acc2[8][2];
  #pragma unroll
  for (int m=0;m<8;++m){ acc1[m][0]=zv; acc1[m][1]=zv; acc2[m][0]=zv; acc2[m][1]=zv; }

  short8 a[8], bb[2];

  KLOOP();

  // ---- epilogue pass 1: residual x into buf0 region, x4 bf16 into buf1 region
  {
    int Cres = colblk*4 + wc;
    #pragma unroll
    for (int i = 0; i < 8; ++i){
      GLL(xb + (((size_t)((rowblk*16 + wr*8 + i)*16 + Cres)) << 10) + lane*16,
          ldsd + ((wv*8 + i) << 10) + lane*16);
    }
    asm volatile("s_waitcnt vmcnt(0)" ::: "memory");
  }
  __syncthreads();

  unsigned short* resU = (unsigned short*)ldsd;
  unsigned short* x4U  = (unsigned short*)(ldsd + 65536);
  float sumsq = 0.f;
  #pragma unroll
  for (int m = 0; m < 8; ++m){
    #pragma unroll
    for (int n = 0; n < 2; ++n){
      #pragma unroll
      for (int r = 0; r < 4; ++r){
        int slot = (quad*4 + r) | ((n*2 + (ln>>3)) << 4);
        int idx = ((wv*8 + m) << 9) + slot*8 + (ln & 7);
        float xv  = b2f(resU[idx]);
        float x1v = acc1[m][n][r];
        float x2v = fmaxf(acc2[m][n][r], 0.f);
        float gate = 1.f + 1.f/(1.f + __expf(-x1v));
        float x4v = fmaf(gate, x2v, xv);
        unsigned short ub = f2b(x4v);
        float fq = b2f(ub);
        sumsq = fmaf(fq, fq, sumsq);
        x4U[idx] = ub;
        acc1[m][n][r] = fq;               // keep quantized value for class-sum pass
      }
    }
  }
  for (int off = 32; off; off >>= 1) sumsq += __shfl_down(sumsq, off);
  __syncthreads();                         // resU region now dead

  // ---- epilogue pass 2: fused class sums (ex-k_csum) in the dead region
  float* table = (float*)ldsd;             // [10][128] f32 = 5120B
  int*   yS    = (int*)(ldsd + 5120);      // 256 labels
  float* red   = (float*)(ldsd + 6144);    // 8 floats
  for (int i = t; i < NC*128; i += 512) table[i] = 0.f;
  if (t < 256) yS[t] = y[rowblk*256 + t];
  if (lane == 0) red[wv] = sumsq;
  __syncthreads();

  {
    int col0 = wc*32 + (ln>>3)*8 + (ln&7);
    #pragma unroll
    for (int m = 0; m < 8; ++m){
      #pragma unroll
      for (int r = 0; r < 4; ++r){
        int c = yS[(wr*8 + m)*16 + quad*4 + r];
        atomicAdd(&table[c*128 + col0],      acc1[m][0][r]);
        atomicAdd(&table[c*128 + col0 + 16], acc1[m][1][r]);
      }
    }
  }

  // copy x4 LDS -> global (16B stores)
  #pragma unroll
  for (int r = 0; r < 2; ++r){
    int o = r*512 + t;
    int tile = o >> 6, off16 = o & 63;
    int wvp = tile >> 3, i = tile & 7;
    size_t Ig = (size_t)rowblk*16 + (wvp>>2)*8 + i;
    int Cg = colblk*4 + (wvp & 3);
    *(short8*)&x4T[((Ig*16 + Cg) << 9) + off16*8] =
      *(const short8*)&x4U[(tile << 9) + off16*8];
  }

  if (t == 0){
    float s = 0.f;
    #pragma unroll
    for (int i=0;i<8;++i) s += red[i];
    atomicAdd(&scal[SCAL_SUMSQ + (blk & (NREP-1))], s);
  }
  __syncthreads();

  // flush class-sum table to global gsum (NREP-sliced)
  {
    size_t base = (size_t)(blk & (NREP-1))*5120 + colblk*128;
    for (int i = t; i < NC*128; i += 512){
      float v = table[i];
      if (v != 0.f)
        atomicAdd(&gsum[base + (i >> 7)*512 + (i & 127)], v);
    }
  }
}

// K2: h = relu(x4 @ w); logits = h @ w1; CE/argmax/acc; LAST block finalizes.
__global__ __launch_bounds__(512, 2) void k_gemm3_head(
    const unsigned short* __restrict__ x4T,
    const unsigned short* __restrict__ wT,
    const unsigned short* __restrict__ w1T,
    const int* __restrict__ y,
    float* __restrict__ accb,
    float* __restrict__ out)
{
  extern __shared__ __align__(16) char ldsd[];   // 131072 dynamic
  __shared__ float redc[8], reda[8];
  __shared__ int lastB;

  float* scal = accb;

  int blk = blockIdx.x;
  int rowblk = blk;                              // 256 rows each
  const int colblk = 0;

  int t = threadIdx.x;
  int wv = t >> 6, lane = t & 63, ln = lane & 15, quad = lane >> 4;
  int wr = wv >> 2, wc = wv & 3;
  int rep = (blk ^ (blk >> 4)) & (NREP-1);

  const char* xb  = (const char*)x4T;
  const char* b0b = (const char*)wT;                       // w cols 0..127 (J 0..7)
  const char* b1b = (const char*)wT + (size_t)128*1024;    // w cols 128..255 (J 8..15)

  const f32x4 zv = {0.f,0.f,0.f,0.f};
  f32x4 acc1[8][2], acc2[8][2];
  #pragma unroll
  for (int m=0;m<8;++m){ acc1[m][0]=zv; acc1[m][1]=zv; acc2[m][0]=zv; acc2[m][1]=zv; }

  short8 a[8], bb[2];

  KLOOP();

  // w1 B-fragments from global (8KB, L2-resident)
  short8 bw1[8];
  #pragma unroll
  for (int Ck = 0; Ck < 8; ++Ck)
    bw1[Ck] = *(const short8*)&w1T[Ck*512 + lane*8];

  // h = relu(acc) fragment-tiled into the (dead) full 128KB LDS
  unsigned short* transH = (unsigned short*)ldsd;
  #pragma unroll
  for (int m = 0; m < 8; ++m){
    #pragma unroll
    for (int n = 0; n < 2; ++n){
      #pragma unroll
      for (int r = 0; r < 4; ++r){
        int slot = (quad*4 + r) | ((n*2 + (ln>>3)) << 4);
        int e = ln & 7;
        int IhA = wr*8 + m;
        transH[((IhA*8 + wc)     << 9) + slot*8 + e] = f2b(fmaxf(acc1[m][n][r], 0.f));
        transH[((IhA*8 + 4 + wc) << 9) + slot*8 + e] = f2b(fmaxf(acc2[m][n][r], 0.f));
      }
    }
  }
  __syncthreads();

  // logits: each wave handles row-tiles Ih = wv*2 + {0,1}
  f32x4 alog[2] = {zv, zv};
  #pragma unroll
  for (int ih = 0; ih < 2; ++ih){
    int Ih = wv*2 + ih;
    #pragma unroll
    for (int Ck = 0; Ck < 8; ++Ck){
      short8 af = *(const short8*)&transH[((Ih*8 + Ck) << 9) + lane*8];
      alog[ih] = __builtin_amdgcn_mfma_f32_16x16x32_bf16(af, bw1[Ck], alog[ih], 0,0,0);
    }
  }

  // CE/argmax: row = blk*256 + Ih*16 + quad*4 + r, class = ln
  float ce_l = 0.f, acc_l = 0.f;
  #pragma unroll
  for (int ih = 0; ih < 2; ++ih){
    #pragma unroll
    for (int r = 0; r < 4; ++r){
      int grow = blk*256 + (wv*2 + ih)*16 + quad*4 + r;
      int yv = y[grow];
      float lg = (ln < NC) ? alog[ih][r] : -1e30f;
      float m = lg; int mi = ln;
      #pragma unroll
      for (int mk = 1; mk < 16; mk <<= 1){
        float om = __shfl_xor(m, mk); int oi = __shfl_xor(mi, mk);
        if (om > m || (om == m && oi < mi)){ m = om; mi = oi; }
      }
      float e  = (ln < NC) ? __expf(lg - m) : 0.f;
      float sy = (ln == yv) ? lg : 0.f;
      #pragma unroll
      for (int mk = 1; mk < 16; mk <<= 1){ e += __shfl_xor(e, mk); sy += __shfl_xor(sy, mk); }
      float lse = m + __logf(e);
      if (ln == 0){ ce_l += (lse - sy); acc_l += (mi == yv) ? 1.f : 0.f; }
    }
  }
  ce_l  += __shfl_down(ce_l, 16);  acc_l += __shfl_down(acc_l, 16);
  ce_l  += __shfl_down(ce_l, 32);  acc_l += __shfl_down(acc_l, 32);
  if (lane == 0){ redc[wv] = ce_l; reda[wv] = acc_l; }
  __syncthreads();
  if (t == 0){
    float c = 0.f, aa = 0.f;
    #pragma unroll
    for (int i=0;i<8;++i){ c += redc[i]; aa += reda[i]; }
    atomicAdd(&scal[SCAL_CE  + rep], c);
    atomicAdd(&scal[SCAL_ACC + rep], aa);
    __threadfence();
    int prev = atomicAdd((int*)(scal + SCAL_CTR), 1);
    lastB = (prev == (int)gridDim.x - 1);
  }
  __syncthreads();
  if (!lastB) return;

  // ---- merged k_final: last block reduces gsum/gcnt/scal -> out
  {
    const float* gsum = accb + GSUM_OFF;
    const float* gcnt = accb + CNT_OFF;
    float contrib = 0.f;
    for (int idx = t; idx < 5120; idx += 512){
      float S = 0.f;
      #pragma unroll
      for (int r = 0; r < NREP; ++r) S += ald(&gsum[(size_t)r*5120 + idx]);
      int c = idx >> 9;
      float cnt = 0.f;
      #pragma unroll
      for (int r = 0; r < NREP; ++r) cnt += ald(&gcnt[r*16 + c]);
      contrib += S*S / fmaxf(cnt, 1.f);
    }
    for (int off = 32; off; off >>= 1) contrib += __shfl_down(contrib, off);
    __syncthreads();                  // redc reusable
    if (lane == 0) redc[wv] = contrib;
    __syncthreads();
    if (t == 0){
      float var2 = 0.f;
      #pragma unroll
      for (int i=0;i<8;++i) var2 += redc[i];
      float sumsq=0.f, ce=0.f, accv=0.f, l1=0.f;
      for (int r=0;r<NREP;++r){
        sumsq += ald(&scal[SCAL_SUMSQ+r]);
        ce    += ald(&scal[SCAL_CE+r]);
        accv  += ald(&scal[SCAL_ACC+r]);
        l1    += ald(&scal[SCAL_L1+r]);
      }
      float var_loss = sumsq - var2;
      out[0] = ce/(float)BATCH + 1e-4f*l1 + 1e-3f*var_loss;
      out[1] = accv/(float)BATCH;
    }
  }
}

extern "C" void kernel_launch(void* const* d_in, const int* in_sizes, int n_in,
                              void* d_out, int out_size, void* d_ws, size_t ws_size,
                              hipStream_t stream){
  (void)in_sizes; (void)n_in; (void)out_size; (void)ws_size;
  const float* x   = (const float*)d_in[0];
  const int*   y   = (const int*)d_in[1];
  const float* fc0 = (const float*)d_in[2];
  const float* fc1 = (const float*)d_in[3];
  const float* w   = (const float*)d_in[4];
  const float* w1  = (const float*)d_in[5];
  char* ws = (char*)d_ws;
  unsigned short* fc0T = (unsigned short*)(ws + OFF_FC0T);
  unsigned short* fc1T = (unsigned short*)(ws + OFF_FC1T);
  unsigned short* wT   = (unsigned short*)(ws + OFF_WT);
  unsigned short* xT   = (unsigned short*)(ws + OFF_XT);
  unsigned short* x4T  = (unsigned short*)(ws + OFF_X4T);
  unsigned short* w1T  = (unsigned short*)(ws + OFF_W1T);
  float* accb = (float*)(ws + OFF_ACC);

  static bool once = [](){
    hipFuncSetAttribute((const void*)k_gemm12,
                        hipFuncAttributeMaxDynamicSharedMemorySize, 131072);
    hipFuncSetAttribute((const void*)k_gemm3_head,
                        hipFuncAttributeMaxDynamicSharedMemorySize, 131072);
    return true;
  }();
  (void)once;

  k_setup<<<1457, 256, 0, stream>>>(x, fc0, fc1, w, w1, y, xT, fc0T, fc1T, wT, w1T, accb);
  k_gemm12<<<1024, 512, 131072, stream>>>(xT, fc0T, fc1T, y, x4T, accb);
  k_gemm3_head<<<256, 512, 131072, stream>>>(x4T, wT, w1T, y, accb, (float*)d_out);
}

// Round 5
// 420.463 us; speedup vs baseline: 1.2098x; 1.2098x over previous
//
#include <hip/hip_runtime.h>
#include <stdint.h>

#define BATCH 65536
#define FDIM 512
#define HDIM 256
#define NC 10
#define NREP 16

typedef short short8 __attribute__((ext_vector_type(8)));
typedef float f32x4 __attribute__((ext_vector_type(4)));

// ---- workspace layout (bytes) ----
// Fragment-tiled layout: tile (I=row/16, C=k/32) is 1KB at (I*nC + C)*1024;
// slot l = (row&15) | (((k>>3)&3)<<4) holds 8 bf16 (k = (l>>4)*8 .. +7).
#define OFF_FC0T   ((size_t)0)                          // 32 J x 16 C tiles
#define OFF_FC1T   (OFF_FC0T + (size_t)512*512*2)
#define OFF_WT     (OFF_FC1T + (size_t)512*512*2)       // 16 J x 16 C tiles
#define OFF_XT     (OFF_WT   + (size_t)256*512*2)       // 4096 I x 16 C (64MB)
#define OFF_X4T    (OFF_XT   + (size_t)BATCH*512*2)     // 4096 I x 16 C (64MB)
#define OFF_ACC    (OFF_X4T  + (size_t)BATCH*512*2)
#define SCAL_SUMSQ 0
#define SCAL_CE    16
#define SCAL_ACC   32
#define SCAL_L1    48
#define SCAL_CTR   64                     // completion counter (int)
#define SCAL_N     128
#define CNT_OFF    SCAL_N                 // NREP*16 floats
#define GSUM_OFF   (SCAL_N + NREP*16)     // NREP*5120 floats
#define ACC_FLOATS (GSUM_OFF + NREP*5120) // 82304 floats
#define OFF_W1T    (OFF_ACC + (size_t)ACC_FLOATS*4)     // 8 C-tiles x 1KB (w1 bf16, padded to 16 classes)

#define GLL(g,l) __builtin_amdgcn_global_load_lds((const __attribute__((address_space(1))) void*)(g), (__attribute__((address_space(3))) void*)(l), 16, 0, 0)

__device__ __forceinline__ unsigned short f2b(float f){
  unsigned u = __float_as_uint(f);
  u += 0x7FFFu + ((u >> 16) & 1u);
  return (unsigned short)(u >> 16);
}
__device__ __forceinline__ float b2f(unsigned short h){
  return __uint_as_float(((unsigned)h) << 16);
}
__device__ __forceinline__ unsigned pk2b(float f0, float f1){
  unsigned u0 = __float_as_uint(f0) + 0x8000u;
  unsigned u1 = __float_as_uint(f1) + 0x8000u;
  return __builtin_amdgcn_perm(u1, u0, 0x07060302u);
}
__device__ __forceinline__ float ald(const float* p){
  return __hip_atomic_load(p, __ATOMIC_RELAXED, __HIP_MEMORY_SCOPE_AGENT);
}

// ---- K0: setup — xcast (0..1023), weight prep (1024..1359), zero (1360..1440),
//      class counts (1441..1456; private slots, no zero dependency)
__global__ __launch_bounds__(256) void k_setup(
    const float* __restrict__ x,   const float* __restrict__ fc0,
    const float* __restrict__ fc1, const float* __restrict__ w,
    const float* __restrict__ w1,  const int* __restrict__ y,
    unsigned short* __restrict__ xT,   unsigned short* __restrict__ fc0T,
    unsigned short* __restrict__ fc1T, unsigned short* __restrict__ wT,
    unsigned short* __restrict__ w1T,  float* __restrict__ accb)
{
  int blk = blockIdx.x, t = threadIdx.x;
  if (blk < 1024){
    // x-cast, contiguous-row reads: wave wv owns I-tile blk*4+wv; per row r the
    // 64 lanes read the full 2KB row (lane l: floats l*8..l*8+7). For lane l all
    // 8 elems share C = l>>2 and slot-high (l&3); slot = r | ((l&3)<<4).
    int wv = t >> 6, l = t & 63;
    int I = blk*4 + wv;
    const float* rowbase = x + ((size_t)I*16)*FDIM + l*8;
    unsigned short* tb = xT + (((size_t)I*16) << 9) + ((size_t)(l >> 2))*512 + (l & 3)*128;
    #pragma unroll
    for (int r = 0; r < 16; ++r){
      float4 v0 = *(const float4*)(rowbase + (size_t)r*FDIM);
      float4 v1 = *(const float4*)(rowbase + (size_t)r*FDIM + 4);
      unsigned o[4];
      o[0] = pk2b(v0.x, v0.y); o[1] = pk2b(v0.z, v0.w);
      o[2] = pk2b(v1.x, v1.y); o[3] = pk2b(v1.z, v1.w);
      *(short8*)&tb[r*8] = *(short8*)o;
    }
    return;
  }
  if (blk < 1360){
    int i = (blk - 1024)*256 + t;
    float l1v = 0.f;
    if (i < 32768){                       // fc0 [k][512] -> tiled
      int n4 = i&15, m = (i>>4)&3, C = (i>>6)&15, J = i>>10;
      int n = J*16+n4, k8 = C*4+m;
      unsigned short o[8];
      #pragma unroll
      for (int j=0;j<8;++j){ float v = fc0[(size_t)(k8*8+j)*512 + n]; o[j]=f2b(v); l1v += fabsf(v); }
      *(short8*)&fc0T[(size_t)(J*16+C)*512 + (i&63)*8] = *(short8*)o;
    } else if (i < 65536){                // fc1
      int j0 = i - 32768;
      int n4 = j0&15, m = (j0>>4)&3, C = (j0>>6)&15, J = j0>>10;
      int n = J*16+n4, k8 = C*4+m;
      unsigned short o[8];
      #pragma unroll
      for (int j=0;j<8;++j){ float v = fc1[(size_t)(k8*8+j)*512 + n]; o[j]=f2b(v); l1v += fabsf(v); }
      *(short8*)&fc1T[(size_t)(J*16+C)*512 + (j0&63)*8] = *(short8*)o;
    } else if (i < 81920){                // w [k][256]
      int j0 = i - 65536;
      int n4 = j0&15, m = (j0>>4)&3, C = (j0>>6)&15, J = j0>>10;
      int n = J*16+n4, k8 = C*4+m;
      unsigned short o[8];
      #pragma unroll
      for (int j=0;j<8;++j){ float v = w[(size_t)(k8*8+j)*256 + n]; o[j]=f2b(v); l1v += fabsf(v); }
      *(short8*)&wT[(size_t)(J*16+C)*512 + (j0&63)*8] = *(short8*)o;
    } else if (i < 86016){                // w1 -> B-fragment tiles (16 classes padded), + L1
      int j0 = i - 81920;                 // 0..4095, one bf16 each
      int C = j0 >> 9, l = (j0 >> 3) & 63, e = j0 & 7;
      int n = l & 15, k = C*32 + (l>>4)*8 + e;
      float v = (n < NC) ? w1[k*NC + n] : 0.f;
      w1T[C*512 + l*8 + e] = f2b(v);
      if (n < NC) l1v = fabsf(v);
    }
    for (int off = 32; off; off >>= 1) l1v += __shfl_down(l1v, off);
    if ((t & 63) == 0 && l1v != 0.f)
      atomicAdd(&accb[SCAL_L1 + (blk & (NREP-1))], l1v);
    return;
  }
  if (blk < 1441){
    int base = (blk - 1360)*1024;
    #pragma unroll
    for (int j=0;j<4;++j){
      int idx = base + j*256 + t;
      // exclude CNT region [CNT_OFF, CNT_OFF+256): fully written by cnt blocks
      if (idx < ACC_FLOATS && (idx < CNT_OFF || idx >= CNT_OFF + NREP*16))
        accb[idx] = 0.f;
    }
    return;
  }
  {
    // class counts: 16 blocks, 4096 labels each, private gcnt slot
    __shared__ float cntS[16];
    int b = blk - 1441;
    if (t < 16) cntS[t] = 0.f;
    __syncthreads();
    int base = b*4096;
    for (int i = t; i < 4096; i += 256) atomicAdd(&cntS[y[base+i]], 1.f);
    __syncthreads();
    if (t < 16) accb[CNT_OFF + b*16 + t] = cntS[t];
  }
}

// ---------------------------------------------------------------------------
// 8-phase fine-interleaved K-loop (round-3 verified). Block = 256 rows x
// (128 cols x 2 matrices); 8 waves; BK=64; double-buffered 128KB LDS
// (per buffer: A 32KB @0, B0 16KB @32K, B1 16KB @48K).
// ---------------------------------------------------------------------------

#define BARRIER() __builtin_amdgcn_s_barrier()
#define LGKM0() do{ asm volatile("s_waitcnt lgkmcnt(0)" ::: "memory"); \
                    __builtin_amdgcn_sched_barrier(0); }while(0)

#define RA(AB, C) do{                                                         \
  _Pragma("unroll") for (int m_=0;m_<8;++m_)                                  \
    a[m_] = *(const short8*)((AB) + (((wr*8+m_)*2 + (C))<<10) + lane*16);     \
}while(0)

#define RB(AB, MAT, C) do{                                                    \
  _Pragma("unroll") for (int n_=0;n_<2;++n_)                                  \
    bb[n_] = *(const short8*)((AB) + 32768 + (MAT)*16384 +                    \
                              (((wc*2+n_)*2 + (C))<<10) + lane*16);           \
}while(0)

#define MM16(ACC) do{                                                         \
  __builtin_amdgcn_s_setprio(1);                                              \
  _Pragma("unroll") for (int n_=0;n_<2;++n_)                                  \
  _Pragma("unroll") for (int m_=0;m_<8;++m_)                                  \
    ACC[m_][n_] = __builtin_amdgcn_mfma_f32_16x16x32_bf16(a[m_], bb[n_], ACC[m_][n_], 0,0,0); \
  __builtin_amdgcn_s_setprio(0);                                              \
}while(0)

#define SA(KT, C) do{                                                         \
  char* d_ = ldsd + (((KT)&1) ? 65536 : 0);                                   \
  _Pragma("unroll") for (int r_=0;r_<2;++r_){                                 \
    int I_ = wv + r_*8;                                                       \
    GLL(xb + (((size_t)((rowblk*16 + I_)*16 + (KT)*2 + (C))) << 10) + lane*16,\
        d_ + ((I_*2 + (C)) << 10) + lane*16);                                 \
  } }while(0)

#define SB(KT, C) do{                                                         \
  char* d_ = ldsd + (((KT)&1) ? 65536 : 0) + 32768;                           \
  GLL(b0b + (((size_t)((colblk*8 + wv)*16 + (KT)*2 + (C))) << 10) + lane*16,  \
      d_ + ((wv*2 + (C)) << 10) + lane*16);                                   \
  GLL(b1b + (((size_t)((colblk*8 + wv)*16 + (KT)*2 + (C))) << 10) + lane*16,  \
      d_ + 16384 + ((wv*2 + (C)) << 10) + lane*16);                           \
}while(0)

#define KLOOP() do{                                                           \
  SA(0,0); SB(0,0); SA(0,1); SB(0,1); SA(1,0); SB(1,0); SA(1,1);              \
  asm volatile("s_waitcnt vmcnt(6)" ::: "memory");                            \
  __builtin_amdgcn_sched_barrier(0);                                          \
  BARRIER();                                                                  \
  _Pragma("unroll")                                                           \
  for (int i = 0; i < 4; ++i){                                                \
    int kt0 = 2*i, kt1 = 2*i+1;                                               \
    char* Ab0 = ldsd + ((kt0 & 1) ? 65536 : 0);                               \
    char* Ab1 = ldsd + ((kt1 & 1) ? 65536 : 0);                               \
    RA(Ab0, 0); RB(Ab0, 0, 0);                                                \
    SB(kt1, 1);                                                               \
    BARRIER(); LGKM0(); MM16(acc1);                                           \
    BARRIER();                                                                \
    RB(Ab0, 1, 0);                                                            \
    if (i < 3) SA(kt0+2, 0);                                                  \
    BARRIER(); LGKM0(); MM16(acc2);                                           \
    BARRIER();                                                                \
    RA(Ab0, 1); RB(Ab0, 0, 1);                                                \
    if (i < 3) SB(kt0+2, 0);                                                  \
    BARRIER(); LGKM0(); MM16(acc1);                                           \
    BARRIER();                                                                \
    RB(Ab0, 1, 1);                                                            \
    if (i < 3) SA(kt0+2, 1);                                                  \
    BARRIER(); LGKM0(); MM16(acc2);                                           \
    if (i < 3) { asm volatile("s_waitcnt vmcnt(6)" ::: "memory"); }           \
    else       { asm volatile("s_waitcnt vmcnt(0)" ::: "memory"); }           \
    __builtin_amdgcn_sched_barrier(0);                                        \
    BARRIER();                                                                \
    RA(Ab1, 0); RB(Ab1, 0, 0);                                                \
    if (i < 3) SB(kt0+2, 1);                                                  \
    BARRIER(); LGKM0(); MM16(acc1);                                           \
    BARRIER();                                                                \
    RB(Ab1, 1, 0);                                                            \
    if (i < 3) SA(kt1+2, 0);                                                  \
    BARRIER(); LGKM0(); MM16(acc2);                                           \
    BARRIER();                                                                \
    RA(Ab1, 1); RB(Ab1, 0, 1);                                                \
    if (i < 3) SB(kt1+2, 0);                                                  \
    BARRIER(); LGKM0(); MM16(acc1);                                           \
    BARRIER();                                                                \
    RB(Ab1, 1, 1);                                                            \
    if (i < 3) SA(kt1+2, 1);                                                  \
    BARRIER(); LGKM0(); MM16(acc2);                                           \
    if (i < 3) { asm volatile("s_waitcnt vmcnt(6)" ::: "memory");             \
                 __builtin_amdgcn_sched_barrier(0); }                         \
    BARRIER();                                                                \
  }                                                                           \
}while(0)

// K1: dual GEMM x@fc0, x@fc1 + gated residual epilogue (round-3 proven form).
__global__ __launch_bounds__(512, 2) void k_gemm12(
    const unsigned short* __restrict__ xT,
    const unsigned short* __restrict__ fc0T,
    const unsigned short* __restrict__ fc1T,
    unsigned short* __restrict__ x4T,
    float* __restrict__ scal)
{
  extern __shared__ __align__(16) char ldsd[];   // 131072 dynamic

  int blk = blockIdx.x;
  int wg = (blk & 7)*128 + (blk >> 3);           // bijective XCD chunking (1024%8==0)
  int rowblk = wg >> 2;                          // 0..255 (256 rows each)
  int colblk = wg & 3;                           // 0..3   (128 cols each)

  int t = threadIdx.x;
  int wv = t >> 6, lane = t & 63, ln = lane & 15, quad = lane >> 4;
  int wr = wv >> 2, wc = wv & 3;                 // 2 x 4 wave grid

  const char* xb  = (const char*)xT;
  const char* b0b = (const char*)fc0T;
  const char* b1b = (const char*)fc1T;

  const f32x4 zv = {0.f,0.f,0.f,0.f};
  f32x4 acc1[8][2], acc2[8][2];
  #pragma unroll
  for (int m=0;m<8;++m){ acc1[m][0]=zv; acc1[m][1]=zv; acc2[m][0]=zv; acc2[m][1]=zv; }

  short8 a[8], bb[2];

  KLOOP();

  // ---- epilogue: residual x into buf0 region, x4 bf16 into buf1 region
  {
    int Cres = colblk*4 + wc;
    #pragma unroll
    for (int i = 0; i < 8; ++i){
      GLL(xb + (((size_t)((rowblk*16 + wr*8 + i)*16 + Cres)) << 10) + lane*16,
          ldsd + ((wv*8 + i) << 10) + lane*16);
    }
    asm volatile("s_waitcnt vmcnt(0)" ::: "memory");
  }
  __syncthreads();

  unsigned short* resU = (unsigned short*)ldsd;
  unsigned short* x4U  = (unsigned short*)(ldsd + 65536);
  float sumsq = 0.f;
  #pragma unroll
  for (int m = 0; m < 8; ++m){
    #pragma unroll
    for (int n = 0; n < 2; ++n){
      #pragma unroll
      for (int r = 0; r < 4; ++r){
        int slot = (quad*4 + r) | ((n*2 + (ln>>3)) << 4);
        int idx = ((wv*8 + m) << 9) + slot*8 + (ln & 7);
        float xv  = b2f(resU[idx]);
        float x1v = acc1[m][n][r];
        float x2v = fmaxf(acc2[m][n][r], 0.f);
        float gate = 1.f + 1.f/(1.f + __expf(-x1v));
        float x4v = fmaf(gate, x2v, xv);
        unsigned short ub = f2b(x4v);
        float fq = b2f(ub);
        sumsq = fmaf(fq, fq, sumsq);
        x4U[idx] = ub;
      }
    }
  }
  for (int off = 32; off; off >>= 1) sumsq += __shfl_down(sumsq, off);
  __syncthreads();                         // all res reads + x4 writes done
  float* red = (float*)ldsd;               // overwrite dead res region
  if (lane == 0) red[wv] = sumsq;
  __syncthreads();
  if (t == 0){
    float s = 0.f;
    #pragma unroll
    for (int i=0;i<8;++i) s += red[i];
    atomicAdd(&scal[SCAL_SUMSQ + (blk & (NREP-1))], s);
  }
  // copy x4 LDS -> global (16B stores)
  #pragma unroll
  for (int r = 0; r < 2; ++r){
    int o = r*512 + t;
    int tile = o >> 6, off16 = o & 63;
    int wvp = tile >> 3, i = tile & 7;
    size_t Ig = (size_t)rowblk*16 + (wvp>>2)*8 + i;
    int Cg = colblk*4 + (wvp & 3);
    *(short8*)&x4T[((Ig*16 + Cg) << 9) + off16*8] =
      *(const short8*)&x4U[(tile << 9) + off16*8];
  }
}

// class sums from tiled x4: one wave per (C-phase, 64 I-tiles); y staged in LDS
__global__ __launch_bounds__(256) void k_csum(const unsigned short* __restrict__ x4T,
                                              const int* __restrict__ y,
                                              float* __restrict__ gsum){
  __shared__ int yS[1024];
  int t = threadIdx.x;
  int wv = t >> 6, l = t & 63;
  int w = blockIdx.x*4 + wv;                   // 1024 waves
  int C = w & 15, Ig = w >> 4;                 // Ig 0..63 (same for all 4 waves)
  int rl = l & 15, q = l >> 4;
  for (int i = t; i < 1024; i += 256) yS[i] = y[Ig*1024 + i];
  __syncthreads();
  float a[NC][8];
  #pragma unroll
  for (int c=0;c<NC;++c)
    #pragma unroll
    for (int e=0;e<8;++e) a[c][e]=0.f;
  for (int ii = 0; ii < 64; ++ii){
    int I = Ig*64 + ii;
    int yv = yS[ii*16 + rl];
    short8 v = *(const short8*)&x4T[(((size_t)I*16 + C) << 9) + l*8];
    float f[8];
    #pragma unroll
    for (int e=0;e<8;++e) f[e] = b2f((unsigned short)v[e]);
    #pragma unroll
    for (int c=0;c<NC;++c){
      bool m = (yv == c);
      #pragma unroll
      for (int e=0;e<8;++e) a[c][e] += m ? f[e] : 0.f;
    }
  }
  #pragma unroll
  for (int off = 1; off < 16; off <<= 1)
    #pragma unroll
    for (int c=0;c<NC;++c)
      #pragma unroll
      for (int e=0;e<8;++e) a[c][e] += __shfl_xor(a[c][e], off);
  if (rl == 0){
    int rep = Ig & (NREP-1);
    int kb = C*32 + q*8;
    #pragma unroll
    for (int c=0;c<NC;++c)
      #pragma unroll
      for (int e=0;e<8;++e)
        atomicAdd(&gsum[(size_t)rep*5120 + c*512 + kb + e], a[c][e]);
  }
}

// K2: h = relu(x4 @ w); logits = h @ w1; CE/argmax/acc; LAST block finalizes.
__global__ __launch_bounds__(512, 2) void k_gemm3_head(
    const unsigned short* __restrict__ x4T,
    const unsigned short* __restrict__ wT,
    const unsigned short* __restrict__ w1T,
    const int* __restrict__ y,
    float* __restrict__ accb,
    float* __restrict__ out)
{
  extern __shared__ __align__(16) char ldsd[];   // 131072 dynamic
  __shared__ float redc[8], reda[8];
  __shared__ int lastB;

  float* scal = accb;

  int blk = blockIdx.x;
  int rowblk = blk;                              // 256 rows each
  const int colblk = 0;

  int t = threadIdx.x;
  int wv = t >> 6, lane = t & 63, ln = lane & 15, quad = lane >> 4;
  int wr = wv >> 2, wc = wv & 3;
  int rep = (blk ^ (blk >> 4)) & (NREP-1);

  const char* xb  = (const char*)x4T;
  const char* b0b = (const char*)wT;                       // w cols 0..127 (J 0..7)
  const char* b1b = (const char*)wT + (size_t)128*1024;    // w cols 128..255 (J 8..15)

  const f32x4 zv = {0.f,0.f,0.f,0.f};
  f32x4 acc1[8][2], acc2[8][2];
  #pragma unroll
  for (int m=0;m<8;++m){ acc1[m][0]=zv; acc1[m][1]=zv; acc2[m][0]=zv; acc2[m][1]=zv; }

  short8 a[8], bb[2];

  KLOOP();

  // w1 B-fragments from global (8KB, L2-resident)
  short8 bw1[8];
  #pragma unroll
  for (int Ck = 0; Ck < 8; ++Ck)
    bw1[Ck] = *(const short8*)&w1T[Ck*512 + lane*8];

  // h = relu(acc) fragment-tiled into the (dead) full 128KB LDS
  unsigned short* transH = (unsigned short*)ldsd;
  #pragma unroll
  for (int m = 0; m < 8; ++m){
    #pragma unroll
    for (int n = 0; n < 2; ++n){
      #pragma unroll
      for (int r = 0; r < 4; ++r){
        int slot = (quad*4 + r) | ((n*2 + (ln>>3)) << 4);
        int e = ln & 7;
        int IhA = wr*8 + m;
        transH[((IhA*8 + wc)     << 9) + slot*8 + e] = f2b(fmaxf(acc1[m][n][r], 0.f));
        transH[((IhA*8 + 4 + wc) << 9) + slot*8 + e] = f2b(fmaxf(acc2[m][n][r], 0.f));
      }
    }
  }
  __syncthreads();

  // logits: each wave handles row-tiles Ih = wv*2 + {0,1}
  f32x4 alog[2] = {zv, zv};
  #pragma unroll
  for (int ih = 0; ih < 2; ++ih){
    int Ih = wv*2 + ih;
    #pragma unroll
    for (int Ck = 0; Ck < 8; ++Ck){
      short8 af = *(const short8*)&transH[((Ih*8 + Ck) << 9) + lane*8];
      alog[ih] = __builtin_amdgcn_mfma_f32_16x16x32_bf16(af, bw1[Ck], alog[ih], 0,0,0);
    }
  }

  // CE/argmax: row = blk*256 + Ih*16 + quad*4 + r, class = ln
  float ce_l = 0.f, acc_l = 0.f;
  #pragma unroll
  for (int ih = 0; ih < 2; ++ih){
    #pragma unroll
    for (int r = 0; r < 4; ++r){
      int grow = blk*256 + (wv*2 + ih)*16 + quad*4 + r;
      int yv = y[grow];
      float lg = (ln < NC) ? alog[ih][r] : -1e30f;
      float m = lg; int mi = ln;
      #pragma unroll
      for (int mk = 1; mk < 16; mk <<= 1){
        float om = __shfl_xor(m, mk); int oi = __shfl_xor(mi, mk);
        if (om > m || (om == m && oi < mi)){ m = om; mi = oi; }
      }
      float e  = (ln < NC) ? __expf(lg - m) : 0.f;
      float sy = (ln == yv) ? lg : 0.f;
      #pragma unroll
      for (int mk = 1; mk < 16; mk <<= 1){ e += __shfl_xor(e, mk); sy += __shfl_xor(sy, mk); }
      float lse = m + __logf(e);
      if (ln == 0){ ce_l += (lse - sy); acc_l += (mi == yv) ? 1.f : 0.f; }
    }
  }
  ce_l  += __shfl_down(ce_l, 16);  acc_l += __shfl_down(acc_l, 16);
  ce_l  += __shfl_down(ce_l, 32);  acc_l += __shfl_down(acc_l, 32);
  if (lane == 0){ redc[wv] = ce_l; reda[wv] = acc_l; }
  __syncthreads();
  if (t == 0){
    float c = 0.f, aa = 0.f;
    #pragma unroll
    for (int i=0;i<8;++i){ c += redc[i]; aa += reda[i]; }
    atomicAdd(&scal[SCAL_CE  + rep], c);
    atomicAdd(&scal[SCAL_ACC + rep], aa);
    __threadfence();
    int prev = atomicAdd((int*)(scal + SCAL_CTR), 1);
    lastB = (prev == (int)gridDim.x - 1);
  }
  __syncthreads();
  if (!lastB) return;

  // ---- merged k_final: last block reduces gsum/gcnt/scal -> out
  {
    const float* gsum = accb + GSUM_OFF;
    const float* gcnt = accb + CNT_OFF;
    float contrib = 0.f;
    for (int idx = t; idx < 5120; idx += 512){
      float S = 0.f;
      #pragma unroll
      for (int r = 0; r < NREP; ++r) S += ald(&gsum[(size_t)r*5120 + idx]);
      int c = idx >> 9;
      float cnt = 0.f;
      #pragma unroll
      for (int r = 0; r < NREP; ++r) cnt += ald(&gcnt[r*16 + c]);
      contrib += S*S / fmaxf(cnt, 1.f);
    }
    for (int off = 32; off; off >>= 1) contrib += __shfl_down(contrib, off);
    __syncthreads();                  // redc reusable
    if (lane == 0) redc[wv] = contrib;
    __syncthreads();
    if (t == 0){
      float var2 = 0.f;
      #pragma unroll
      for (int i=0;i<8;++i) var2 += redc[i];
      float sumsq=0.f, ce=0.f, accv=0.f, l1=0.f;
      for (int r=0;r<NREP;++r){
        sumsq += ald(&scal[SCAL_SUMSQ+r]);
        ce    += ald(&scal[SCAL_CE+r]);
        accv  += ald(&scal[SCAL_ACC+r]);
        l1    += ald(&scal[SCAL_L1+r]);
      }
      float var_loss = sumsq - var2;
      out[0] = ce/(float)BATCH + 1e-4f*l1 + 1e-3f*var_loss;
      out[1] = accv/(float)BATCH;
    }
  }
}

extern "C" void kernel_launch(void* const* d_in, const int* in_sizes, int n_in,
                              void* d_out, int out_size, void* d_ws, size_t ws_size,
                              hipStream_t stream){
  (void)in_sizes; (void)n_in; (void)out_size; (void)ws_size;
  const float* x   = (const float*)d_in[0];
  const int*   y   = (const int*)d_in[1];
  const float* fc0 = (const float*)d_in[2];
  const float* fc1 = (const float*)d_in[3];
  const float* w   = (const float*)d_in[4];
  const float* w1  = (const float*)d_in[5];
  char* ws = (char*)d_ws;
  unsigned short* fc0T = (unsigned short*)(ws + OFF_FC0T);
  unsigned short* fc1T = (unsigned short*)(ws + OFF_FC1T);
  unsigned short* wT   = (unsigned short*)(ws + OFF_WT);
  unsigned short* xT   = (unsigned short*)(ws + OFF_XT);
  unsigned short* x4T  = (unsigned short*)(ws + OFF_X4T);
  unsigned short* w1T  = (unsigned short*)(ws + OFF_W1T);
  float* accb = (float*)(ws + OFF_ACC);
  float* scal = accb;
  float* gsum = accb + GSUM_OFF;

  static bool once = [](){
    hipFuncSetAttribute((const void*)k_gemm12,
                        hipFuncAttributeMaxDynamicSharedMemorySize, 131072);
    hipFuncSetAttribute((const void*)k_gemm3_head,
                        hipFuncAttributeMaxDynamicSharedMemorySize, 131072);
    return true;
  }();
  (void)once;

  k_setup<<<1457, 256, 0, stream>>>(x, fc0, fc1, w, w1, y, xT, fc0T, fc1T, wT, w1T, accb);
  k_gemm12<<<1024, 512, 131072, stream>>>(xT, fc0T, fc1T, x4T, scal);
  k_csum<<<256, 256, 0, stream>>>(x4T, y, gsum);
  k_gemm3_head<<<256, 512, 131072, stream>>>(x4T, wT, w1T, y, accb, (float*)d_out);
}

// Round 6
// 393.175 us; speedup vs baseline: 1.2938x; 1.0694x over previous
//
#include <hip/hip_runtime.h>
#include <stdint.h>

#define BATCH 65536
#define FDIM 512
#define HDIM 256
#define NC 10
#define NREP 16

typedef short short8 __attribute__((ext_vector_type(8)));
typedef float f32x4 __attribute__((ext_vector_type(4)));

// ---- workspace layout (bytes) ----
// Fragment-tiled layout: tile (I=row/16, C=k/32) is 1KB at (I*nC + C)*1024;
// slot l = (row&15) | (((k>>3)&3)<<4) holds 8 bf16 (k = (l>>4)*8 .. +7).
#define OFF_FC0T   ((size_t)0)                          // 32 J x 16 C tiles
#define OFF_FC1T   (OFF_FC0T + (size_t)512*512*2)
#define OFF_WT     (OFF_FC1T + (size_t)512*512*2)       // 16 J x 16 C tiles
#define OFF_XT     (OFF_WT   + (size_t)256*512*2)       // 4096 I x 16 C (64MB)
#define OFF_X4T    (OFF_XT   + (size_t)BATCH*512*2)     // 4096 I x 16 C (64MB)
#define OFF_ACC    (OFF_X4T  + (size_t)BATCH*512*2)
#define SCAL_SUMSQ 0
#define SCAL_CE    16
#define SCAL_ACC   32
#define SCAL_L1    48
#define SCAL_CTR   64                     // completion counter (int)
#define SCAL_N     128
#define CNT_OFF    SCAL_N                 // NREP*16 floats
#define GSUM_OFF   (SCAL_N + NREP*16)     // NREP*5120 floats
#define ACC_FLOATS (GSUM_OFF + NREP*5120) // 82304 floats
#define OFF_W1T    (OFF_ACC + (size_t)ACC_FLOATS*4)     // 8 C-tiles x 1KB (w1 bf16, padded to 16 classes)

#define GLL(g,l) __builtin_amdgcn_global_load_lds((const __attribute__((address_space(1))) void*)(g), (__attribute__((address_space(3))) void*)(l), 16, 0, 0)

__device__ __forceinline__ unsigned short f2b(float f){
  unsigned u = __float_as_uint(f);
  u += 0x7FFFu + ((u >> 16) & 1u);
  return (unsigned short)(u >> 16);
}
__device__ __forceinline__ float b2f(unsigned short h){
  return __uint_as_float(((unsigned)h) << 16);
}
__device__ __forceinline__ unsigned pk2b(float f0, float f1){
  unsigned u0 = __float_as_uint(f0) + 0x8000u;
  unsigned u1 = __float_as_uint(f1) + 0x8000u;
  return __builtin_amdgcn_perm(u1, u0, 0x07060302u);
}
__device__ __forceinline__ float ald(const float* p){
  return __hip_atomic_load(p, __ATOMIC_RELAXED, __HIP_MEMORY_SCOPE_AGENT);
}

// ---- K0: setup — xcast (0..1023), weight prep (1024..1359), zero (1360..1440),
//      class counts (1441..1456; private slots, no zero dependency)
__global__ __launch_bounds__(256) void k_setup(
    const float* __restrict__ x,   const float* __restrict__ fc0,
    const float* __restrict__ fc1, const float* __restrict__ w,
    const float* __restrict__ w1,  const int* __restrict__ y,
    unsigned short* __restrict__ xT,   unsigned short* __restrict__ fc0T,
    unsigned short* __restrict__ fc1T, unsigned short* __restrict__ wT,
    unsigned short* __restrict__ w1T,  float* __restrict__ accb)
{
  int blk = blockIdx.x, t = threadIdx.x;
  if (blk < 1024){
    // x-cast via LDS transpose: contiguous 2KB-row reads AND contiguous 1KB
    // tile writes. LDS [16][520] bf16 (pad 8 shorts kills bank aliasing).
    __shared__ __align__(16) unsigned short xls[16*520];
    int wv = t >> 6, l = t & 63;
    #pragma unroll 1
    for (int it = 0; it < 4; ++it){
      int I = blk*4 + it;
      #pragma unroll
      for (int rr = 0; rr < 4; ++rr){
        int row = wv*4 + rr;
        const float* src = x + ((size_t)(I*16 + row))*FDIM + l*8;
        float4 v0 = *(const float4*)src;
        float4 v1 = *(const float4*)(src + 4);
        unsigned o[4];
        o[0] = pk2b(v0.x, v0.y); o[1] = pk2b(v0.z, v0.w);
        o[2] = pk2b(v1.x, v1.y); o[3] = pk2b(v1.z, v1.w);
        *(short8*)&xls[row*520 + l*8] = *(short8*)o;
      }
      __syncthreads();
      #pragma unroll
      for (int cc = 0; cc < 4; ++cc){
        int C = cc*4 + wv;
        short8 v = *(const short8*)&xls[(l & 15)*520 + C*32 + (l >> 4)*8];
        *(short8*)&xT[(((size_t)I*16 + C) << 9) + l*8] = v;
      }
      __syncthreads();
    }
    return;
  }
  if (blk < 1360){
    int i = (blk - 1024)*256 + t;
    float l1v = 0.f;
    if (i < 32768){                       // fc0 [k][512] -> tiled
      int n4 = i&15, m = (i>>4)&3, C = (i>>6)&15, J = i>>10;
      int n = J*16+n4, k8 = C*4+m;
      unsigned short o[8];
      #pragma unroll
      for (int j=0;j<8;++j){ float v = fc0[(size_t)(k8*8+j)*512 + n]; o[j]=f2b(v); l1v += fabsf(v); }
      *(short8*)&fc0T[(size_t)(J*16+C)*512 + (i&63)*8] = *(short8*)o;
    } else if (i < 65536){                // fc1
      int j0 = i - 32768;
      int n4 = j0&15, m = (j0>>4)&3, C = (j0>>6)&15, J = j0>>10;
      int n = J*16+n4, k8 = C*4+m;
      unsigned short o[8];
      #pragma unroll
      for (int j=0;j<8;++j){ float v = fc1[(size_t)(k8*8+j)*512 + n]; o[j]=f2b(v); l1v += fabsf(v); }
      *(short8*)&fc1T[(size_t)(J*16+C)*512 + (j0&63)*8] = *(short8*)o;
    } else if (i < 81920){                // w [k][256]
      int j0 = i - 65536;
      int n4 = j0&15, m = (j0>>4)&3, C = (j0>>6)&15, J = j0>>10;
      int n = J*16+n4, k8 = C*4+m;
      unsigned short o[8];
      #pragma unroll
      for (int j=0;j<8;++j){ float v = w[(size_t)(k8*8+j)*256 + n]; o[j]=f2b(v); l1v += fabsf(v); }
      *(short8*)&wT[(size_t)(J*16+C)*512 + (j0&63)*8] = *(short8*)o;
    } else if (i < 86016){                // w1 -> B-fragment tiles (16 classes padded), + L1
      int j0 = i - 81920;                 // 0..4095, one bf16 each
      int C = j0 >> 9, l = (j0 >> 3) & 63, e = j0 & 7;
      int n = l & 15, k = C*32 + (l>>4)*8 + e;
      float v = (n < NC) ? w1[k*NC + n] : 0.f;
      w1T[C*512 + l*8 + e] = f2b(v);
      if (n < NC) l1v = fabsf(v);
    }
    for (int off = 32; off; off >>= 1) l1v += __shfl_down(l1v, off);
    if ((t & 63) == 0 && l1v != 0.f)
      atomicAdd(&accb[SCAL_L1 + (blk & (NREP-1))], l1v);
    return;
  }
  if (blk < 1441){
    int base = (blk - 1360)*1024;
    #pragma unroll
    for (int j=0;j<4;++j){
      int idx = base + j*256 + t;
      // exclude CNT region [CNT_OFF, CNT_OFF+256): fully written by cnt blocks
      if (idx < ACC_FLOATS && (idx < CNT_OFF || idx >= CNT_OFF + NREP*16))
        accb[idx] = 0.f;
    }
    return;
  }
  {
    // class counts: 16 blocks, 4096 labels each, private gcnt slot
    __shared__ float cntS[16];
    int b = blk - 1441;
    if (t < 16) cntS[t] = 0.f;
    __syncthreads();
    int base = b*4096;
    for (int i = t; i < 4096; i += 256) atomicAdd(&cntS[y[base+i]], 1.f);
    __syncthreads();
    if (t < 16) accb[CNT_OFF + b*16 + t] = cntS[t];
  }
}

// ---------------------------------------------------------------------------
// 8-phase fine-interleaved K-loop (round-3 verified). Block = 256 rows x
// (128 cols x 2 matrices); 8 waves; BK=64; double-buffered 128KB LDS
// (per buffer: A 32KB @0, B0 16KB @32K, B1 16KB @48K).
// ---------------------------------------------------------------------------

#define BARRIER() __builtin_amdgcn_s_barrier()
#define LGKM0() do{ asm volatile("s_waitcnt lgkmcnt(0)" ::: "memory"); \
                    __builtin_amdgcn_sched_barrier(0); }while(0)

#define RA(AB, C) do{                                                         \
  _Pragma("unroll") for (int m_=0;m_<8;++m_)                                  \
    a[m_] = *(const short8*)((AB) + (((wr*8+m_)*2 + (C))<<10) + lane*16);     \
}while(0)

#define RB(AB, MAT, C) do{                                                    \
  _Pragma("unroll") for (int n_=0;n_<2;++n_)                                  \
    bb[n_] = *(const short8*)((AB) + 32768 + (MAT)*16384 +                    \
                              (((wc*2+n_)*2 + (C))<<10) + lane*16);           \
}while(0)

#define MM16(ACC) do{                                                         \
  __builtin_amdgcn_s_setprio(1);                                              \
  _Pragma("unroll") for (int n_=0;n_<2;++n_)                                  \
  _Pragma("unroll") for (int m_=0;m_<8;++m_)                                  \
    ACC[m_][n_] = __builtin_amdgcn_mfma_f32_16x16x32_bf16(a[m_], bb[n_], ACC[m_][n_], 0,0,0); \
  __builtin_amdgcn_s_setprio(0);                                              \
}while(0)

#define SA(KT, C) do{                                                         \
  char* d_ = ldsd + (((KT)&1) ? 65536 : 0);                                   \
  _Pragma("unroll") for (int r_=0;r_<2;++r_){                                 \
    int I_ = wv + r_*8;                                                       \
    GLL(xb + (((size_t)((rowblk*16 + I_)*16 + (KT)*2 + (C))) << 10) + lane*16,\
        d_ + ((I_*2 + (C)) << 10) + lane*16);                                 \
  } }while(0)

#define SB(KT, C) do{                                                         \
  char* d_ = ldsd + (((KT)&1) ? 65536 : 0) + 32768;                           \
  GLL(b0b + (((size_t)((colblk*8 + wv)*16 + (KT)*2 + (C))) << 10) + lane*16,  \
      d_ + ((wv*2 + (C)) << 10) + lane*16);                                   \
  GLL(b1b + (((size_t)((colblk*8 + wv)*16 + (KT)*2 + (C))) << 10) + lane*16,  \
      d_ + 16384 + ((wv*2 + (C)) << 10) + lane*16);                           \
}while(0)

#define KLOOP() do{                                                           \
  SA(0,0); SB(0,0); SA(0,1); SB(0,1); SA(1,0); SB(1,0); SA(1,1);              \
  asm volatile("s_waitcnt vmcnt(6)" ::: "memory");                            \
  __builtin_amdgcn_sched_barrier(0);                                          \
  BARRIER();                                                                  \
  _Pragma("unroll")                                                           \
  for (int i = 0; i < 4; ++i){                                                \
    int kt0 = 2*i, kt1 = 2*i+1;                                               \
    char* Ab0 = ldsd + ((kt0 & 1) ? 65536 : 0);                               \
    char* Ab1 = ldsd + ((kt1 & 1) ? 65536 : 0);                               \
    RA(Ab0, 0); RB(Ab0, 0, 0);                                                \
    SB(kt1, 1);                                                               \
    BARRIER(); LGKM0(); MM16(acc1);                                           \
    BARRIER();                                                                \
    RB(Ab0, 1, 0);                                                            \
    if (i < 3) SA(kt0+2, 0);                                                  \
    BARRIER(); LGKM0(); MM16(acc2);                                           \
    BARRIER();                                                                \
    RA(Ab0, 1); RB(Ab0, 0, 1);                                                \
    if (i < 3) SB(kt0+2, 0);                                                  \
    BARRIER(); LGKM0(); MM16(acc1);                                           \
    BARRIER();                                                                \
    RB(Ab0, 1, 1);                                                            \
    if (i < 3) SA(kt0+2, 1);                                                  \
    BARRIER(); LGKM0(); MM16(acc2);                                           \
    if (i < 3) { asm volatile("s_waitcnt vmcnt(6)" ::: "memory"); }           \
    else       { asm volatile("s_waitcnt vmcnt(0)" ::: "memory"); }           \
    __builtin_amdgcn_sched_barrier(0);                                        \
    BARRIER();                                                                \
    RA(Ab1, 0); RB(Ab1, 0, 0);                                                \
    if (i < 3) SB(kt0+2, 1);                                                  \
    BARRIER(); LGKM0(); MM16(acc1);                                           \
    BARRIER();                                                                \
    RB(Ab1, 1, 0);                                                            \
    if (i < 3) SA(kt1+2, 0);                                                  \
    BARRIER(); LGKM0(); MM16(acc2);                                           \
    BARRIER();                                                                \
    RA(Ab1, 1); RB(Ab1, 0, 1);                                                \
    if (i < 3) SB(kt1+2, 0);                                                  \
    BARRIER(); LGKM0(); MM16(acc1);                                           \
    BARRIER();                                                                \
    RB(Ab1, 1, 1);                                                            \
    if (i < 3) SA(kt1+2, 1);                                                  \
    BARRIER(); LGKM0(); MM16(acc2);                                           \
    if (i < 3) { asm volatile("s_waitcnt vmcnt(6)" ::: "memory");             \
                 __builtin_amdgcn_sched_barrier(0); }                         \
    BARRIER();                                                                \
  }                                                                           \
}while(0)

// K1: dual GEMM x@fc0, x@fc1 + gated residual epilogue (round-3 proven form).
__global__ __launch_bounds__(512, 2) void k_gemm12(
    const unsigned short* __restrict__ xT,
    const unsigned short* __restrict__ fc0T,
    const unsigned short* __restrict__ fc1T,
    unsigned short* __restrict__ x4T,
    float* __restrict__ scal)
{
  extern __shared__ __align__(16) char ldsd[];   // 131072 dynamic

  int blk = blockIdx.x;
  int wg = (blk & 7)*128 + (blk >> 3);           // bijective XCD chunking (1024%8==0)
  int rowblk = wg >> 2;                          // 0..255 (256 rows each)
  int colblk = wg & 3;                           // 0..3   (128 cols each)

  int t = threadIdx.x;
  int wv = t >> 6, lane = t & 63, ln = lane & 15, quad = lane >> 4;
  int wr = wv >> 2, wc = wv & 3;                 // 2 x 4 wave grid

  const char* xb  = (const char*)xT;
  const char* b0b = (const char*)fc0T;
  const char* b1b = (const char*)fc1T;

  const f32x4 zv = {0.f,0.f,0.f,0.f};
  f32x4 acc1[8][2], acc2[8][2];
  #pragma unroll
  for (int m=0;m<8;++m){ acc1[m][0]=zv; acc1[m][1]=zv; acc2[m][0]=zv; acc2[m][1]=zv; }

  short8 a[8], bb[2];

  KLOOP();

  // ---- epilogue: residual x into buf0 region, x4 bf16 into buf1 region
  {
    int Cres = colblk*4 + wc;
    #pragma unroll
    for (int i = 0; i < 8; ++i){
      GLL(xb + (((size_t)((rowblk*16 + wr*8 + i)*16 + Cres)) << 10) + lane*16,
          ldsd + ((wv*8 + i) << 10) + lane*16);
    }
    asm volatile("s_waitcnt vmcnt(0)" ::: "memory");
  }
  __syncthreads();

  unsigned short* resU = (unsigned short*)ldsd;
  unsigned short* x4U  = (unsigned short*)(ldsd + 65536);
  float sumsq = 0.f;
  #pragma unroll
  for (int m = 0; m < 8; ++m){
    #pragma unroll
    for (int n = 0; n < 2; ++n){
      #pragma unroll
      for (int r = 0; r < 4; ++r){
        int slot = (quad*4 + r) | ((n*2 + (ln>>3)) << 4);
        int idx = ((wv*8 + m) << 9) + slot*8 + (ln & 7);
        float xv  = b2f(resU[idx]);
        float x1v = acc1[m][n][r];
        float x2v = fmaxf(acc2[m][n][r], 0.f);
        float gate = 1.f + 1.f/(1.f + __expf(-x1v));
        float x4v = fmaf(gate, x2v, xv);
        unsigned short ub = f2b(x4v);
        float fq = b2f(ub);
        sumsq = fmaf(fq, fq, sumsq);
        x4U[idx] = ub;
      }
    }
  }
  for (int off = 32; off; off >>= 1) sumsq += __shfl_down(sumsq, off);
  __syncthreads();                         // all res reads + x4 writes done
  float* red = (float*)ldsd;               // overwrite dead res region
  if (lane == 0) red[wv] = sumsq;
  __syncthreads();
  if (t == 0){
    float s = 0.f;
    #pragma unroll
    for (int i=0;i<8;++i) s += red[i];
    atomicAdd(&scal[SCAL_SUMSQ + (blk & (NREP-1))], s);
  }
  // copy x4 LDS -> global (16B stores)
  #pragma unroll
  for (int r = 0; r < 2; ++r){
    int o = r*512 + t;
    int tile = o >> 6, off16 = o & 63;
    int wvp = tile >> 3, i = tile & 7;
    size_t Ig = (size_t)rowblk*16 + (wvp>>2)*8 + i;
    int Cg = colblk*4 + (wvp & 3);
    *(short8*)&x4T[((Ig*16 + Cg) << 9) + off16*8] =
      *(const short8*)&x4U[(tile << 9) + off16*8];
  }
}

// class sums from tiled x4: one wave per (C-phase, 64 I-tiles); y staged in LDS
__global__ __launch_bounds__(256) void k_csum(const unsigned short* __restrict__ x4T,
                                              const int* __restrict__ y,
                                              float* __restrict__ gsum){
  __shared__ int yS[1024];
  int t = threadIdx.x;
  int wv = t >> 6, l = t & 63;
  int w = blockIdx.x*4 + wv;                   // 1024 waves
  int C = w & 15, Ig = w >> 4;                 // Ig 0..63 (same for all 4 waves)
  int rl = l & 15, q = l >> 4;
  for (int i = t; i < 1024; i += 256) yS[i] = y[Ig*1024 + i];
  __syncthreads();
  float a[NC][8];
  #pragma unroll
  for (int c=0;c<NC;++c)
    #pragma unroll
    for (int e=0;e<8;++e) a[c][e]=0.f;
  for (int ii = 0; ii < 64; ++ii){
    int I = Ig*64 + ii;
    int yv = yS[ii*16 + rl];
    short8 v = *(const short8*)&x4T[(((size_t)I*16 + C) << 9) + l*8];
    float f[8];
    #pragma unroll
    for (int e=0;e<8;++e) f[e] = b2f((unsigned short)v[e]);
    #pragma unroll
    for (int c=0;c<NC;++c){
      bool m = (yv == c);
      #pragma unroll
      for (int e=0;e<8;++e) a[c][e] += m ? f[e] : 0.f;
    }
  }
  #pragma unroll
  for (int off = 1; off < 16; off <<= 1)
    #pragma unroll
    for (int c=0;c<NC;++c)
      #pragma unroll
      for (int e=0;e<8;++e) a[c][e] += __shfl_xor(a[c][e], off);
  if (rl == 0){
    int rep = Ig & (NREP-1);
    int kb = C*32 + q*8;
    #pragma unroll
    for (int c=0;c<NC;++c)
      #pragma unroll
      for (int e=0;e<8;++e)
        atomicAdd(&gsum[(size_t)rep*5120 + c*512 + kb + e], a[c][e]);
  }
}

// K2: h = relu(x4 @ w); logits = h @ w1; CE/argmax/acc; LAST block finalizes.
__global__ __launch_bounds__(512, 2) void k_gemm3_head(
    const unsigned short* __restrict__ x4T,
    const unsigned short* __restrict__ wT,
    const unsigned short* __restrict__ w1T,
    const int* __restrict__ y,
    float* __restrict__ accb,
    float* __restrict__ out)
{
  extern __shared__ __align__(16) char ldsd[];   // 131072 dynamic
  __shared__ float redc[8], reda[8];
  __shared__ int lastB;

  float* scal = accb;

  int blk = blockIdx.x;
  int rowblk = blk;                              // 256 rows each
  const int colblk = 0;

  int t = threadIdx.x;
  int wv = t >> 6, lane = t & 63, ln = lane & 15, quad = lane >> 4;
  int wr = wv >> 2, wc = wv & 3;
  int rep = (blk ^ (blk >> 4)) & (NREP-1);

  const char* xb  = (const char*)x4T;
  const char* b0b = (const char*)wT;                       // w cols 0..127 (J 0..7)
  const char* b1b = (const char*)wT + (size_t)128*1024;    // w cols 128..255 (J 8..15)

  const f32x4 zv = {0.f,0.f,0.f,0.f};
  f32x4 acc1[8][2], acc2[8][2];
  #pragma unroll
  for (int m=0;m<8;++m){ acc1[m][0]=zv; acc1[m][1]=zv; acc2[m][0]=zv; acc2[m][1]=zv; }

  short8 a[8], bb[2];

  KLOOP();

  // w1 B-fragments from global (8KB, L2-resident)
  short8 bw1[8];
  #pragma unroll
  for (int Ck = 0; Ck < 8; ++Ck)
    bw1[Ck] = *(const short8*)&w1T[Ck*512 + lane*8];

  // h = relu(acc) fragment-tiled into the (dead) full 128KB LDS
  unsigned short* transH = (unsigned short*)ldsd;
  #pragma unroll
  for (int m = 0; m < 8; ++m){
    #pragma unroll
    for (int n = 0; n < 2; ++n){
      #pragma unroll
      for (int r = 0; r < 4; ++r){
        int slot = (quad*4 + r) | ((n*2 + (ln>>3)) << 4);
        int e = ln & 7;
        int IhA = wr*8 + m;
        transH[((IhA*8 + wc)     << 9) + slot*8 + e] = f2b(fmaxf(acc1[m][n][r], 0.f));
        transH[((IhA*8 + 4 + wc) << 9) + slot*8 + e] = f2b(fmaxf(acc2[m][n][r], 0.f));
      }
    }
  }
  __syncthreads();

  // logits: each wave handles row-tiles Ih = wv*2 + {0,1}
  f32x4 alog[2] = {zv, zv};
  #pragma unroll
  for (int ih = 0; ih < 2; ++ih){
    int Ih = wv*2 + ih;
    #pragma unroll
    for (int Ck = 0; Ck < 8; ++Ck){
      short8 af = *(const short8*)&transH[((Ih*8 + Ck) << 9) + lane*8];
      alog[ih] = __builtin_amdgcn_mfma_f32_16x16x32_bf16(af, bw1[Ck], alog[ih], 0,0,0);
    }
  }

  // CE/argmax: row = blk*256 + Ih*16 + quad*4 + r, class = ln
  float ce_l = 0.f, acc_l = 0.f;
  #pragma unroll
  for (int ih = 0; ih < 2; ++ih){
    #pragma unroll
    for (int r = 0; r < 4; ++r){
      int grow = blk*256 + (wv*2 + ih)*16 + quad*4 + r;
      int yv = y[grow];
      float lg = (ln < NC) ? alog[ih][r] : -1e30f;
      float m = lg; int mi = ln;
      #pragma unroll
      for (int mk = 1; mk < 16; mk <<= 1){
        float om = __shfl_xor(m, mk); int oi = __shfl_xor(mi, mk);
        if (om > m || (om == m && oi < mi)){ m = om; mi = oi; }
      }
      float e  = (ln < NC) ? __expf(lg - m) : 0.f;
      float sy = (ln == yv) ? lg : 0.f;
      #pragma unroll
      for (int mk = 1; mk < 16; mk <<= 1){ e += __shfl_xor(e, mk); sy += __shfl_xor(sy, mk); }
      float lse = m + __logf(e);
      if (ln == 0){ ce_l += (lse - sy); acc_l += (mi == yv) ? 1.f : 0.f; }
    }
  }
  ce_l  += __shfl_down(ce_l, 16);  acc_l += __shfl_down(acc_l, 16);
  ce_l  += __shfl_down(ce_l, 32);  acc_l += __shfl_down(acc_l, 32);
  if (lane == 0){ redc[wv] = ce_l; reda[wv] = acc_l; }
  __syncthreads();
  if (t == 0){
    float c = 0.f, aa = 0.f;
    #pragma unroll
    for (int i=0;i<8;++i){ c += redc[i]; aa += reda[i]; }
    atomicAdd(&scal[SCAL_CE  + rep], c);
    atomicAdd(&scal[SCAL_ACC + rep], aa);
    __threadfence();
    int prev = atomicAdd((int*)(scal + SCAL_CTR), 1);
    lastB = (prev == (int)gridDim.x - 1);
  }
  __syncthreads();
  if (!lastB) return;

  // ---- merged k_final: last block reduces gsum/gcnt/scal -> out
  {
    const float* gsum = accb + GSUM_OFF;
    const float* gcnt = accb + CNT_OFF;
    float contrib = 0.f;
    for (int idx = t; idx < 5120; idx += 512){
      float S = 0.f;
      #pragma unroll
      for (int r = 0; r < NREP; ++r) S += ald(&gsum[(size_t)r*5120 + idx]);
      int c = idx >> 9;
      float cnt = 0.f;
      #pragma unroll
      for (int r = 0; r < NREP; ++r) cnt += ald(&gcnt[r*16 + c]);
      contrib += S*S / fmaxf(cnt, 1.f);
    }
    for (int off = 32; off; off >>= 1) contrib += __shfl_down(contrib, off);
    __syncthreads();                  // redc reusable
    if (lane == 0) redc[wv] = contrib;
    __syncthreads();
    if (t == 0){
      float var2 = 0.f;
      #pragma unroll
      for (int i=0;i<8;++i) var2 += redc[i];
      float sumsq=0.f, ce=0.f, accv=0.f, l1=0.f;
      for (int r=0;r<NREP;++r){
        sumsq += ald(&scal[SCAL_SUMSQ+r]);
        ce    += ald(&scal[SCAL_CE+r]);
        accv  += ald(&scal[SCAL_ACC+r]);
        l1    += ald(&scal[SCAL_L1+r]);
      }
      float var_loss = sumsq - var2;
      out[0] = ce/(float)BATCH + 1e-4f*l1 + 1e-3f*var_loss;
      out[1] = accv/(float)BATCH;
    }
  }
}

extern "C" void kernel_launch(void* const* d_in, const int* in_sizes, int n_in,
                              void* d_out, int out_size, void* d_ws, size_t ws_size,
                              hipStream_t stream){
  (void)in_sizes; (void)n_in; (void)out_size; (void)ws_size;
  const float* x   = (const float*)d_in[0];
  const int*   y   = (const int*)d_in[1];
  const float* fc0 = (const float*)d_in[2];
  const float* fc1 = (const float*)d_in[3];
  const float* w   = (const float*)d_in[4];
  const float* w1  = (const float*)d_in[5];
  char* ws = (char*)d_ws;
  unsigned short* fc0T = (unsigned short*)(ws + OFF_FC0T);
  unsigned short* fc1T = (unsigned short*)(ws + OFF_FC1T);
  unsigned short* wT   = (unsigned short*)(ws + OFF_WT);
  unsigned short* xT   = (unsigned short*)(ws + OFF_XT);
  unsigned short* x4T  = (unsigned short*)(ws + OFF_X4T);
  unsigned short* w1T  = (unsigned short*)(ws + OFF_W1T);
  float* accb = (float*)(ws + OFF_ACC);
  float* scal = accb;
  float* gsum = accb + GSUM_OFF;

  static bool once = [](){
    hipFuncSetAttribute((const void*)k_gemm12,
                        hipFuncAttributeMaxDynamicSharedMemorySize, 131072);
    hipFuncSetAttribute((const void*)k_gemm3_head,
                        hipFuncAttributeMaxDynamicSharedMemorySize, 131072);
    return true;
  }();
  (void)once;

  k_setup<<<1457, 256, 0, stream>>>(x, fc0, fc1, w, w1, y, xT, fc0T, fc1T, wT, w1T, accb);
  k_gemm12<<<1024, 512, 131072, stream>>>(xT, fc0T, fc1T, x4T, scal);
  k_csum<<<256, 256, 0, stream>>>(x4T, y, gsum);
  k_gemm3_head<<<256, 512, 131072, stream>>>(x4T, wT, w1T, y, accb, (float*)d_out);
}

// Round 7
// 354.802 us; speedup vs baseline: 1.4337x; 1.1082x over previous
//
#include <hip/hip_runtime.h>
#include <stdint.h>

#define BATCH 65536
#define FDIM 512
#define HDIM 256
#define NC 10
#define NREP 16

typedef short short8 __attribute__((ext_vector_type(8)));
typedef float f32x4 __attribute__((ext_vector_type(4)));

// ---- workspace layout (bytes) ----
// Fragment-tiled layout: tile (I=row/16, C=k/32) is 1KB at (I*nC + C)*1024;
// slot l = (row&15) | (((k>>3)&3)<<4) holds 8 bf16 (k = (l>>4)*8 .. +7).
#define OFF_FC0T   ((size_t)0)                          // 32 J x 16 C tiles
#define OFF_FC1T   (OFF_FC0T + (size_t)512*512*2)
#define OFF_WT     (OFF_FC1T + (size_t)512*512*2)       // 16 J x 16 C tiles
#define OFF_XT     (OFF_WT   + (size_t)256*512*2)       // 4096 I x 16 C (64MB)
#define OFF_X4T    (OFF_XT   + (size_t)BATCH*512*2)     // 4096 I x 16 C (64MB)
#define OFF_ACC    (OFF_X4T  + (size_t)BATCH*512*2)
#define SCAL_SUMSQ 0
#define SCAL_CE    16
#define SCAL_ACC   32
#define SCAL_L1    48
#define SCAL_CTR   64                     // completion counter (int)
#define SCAL_N     128
#define CNT_OFF    SCAL_N                 // NREP*16 floats
#define GSUM_OFF   (SCAL_N + NREP*16)     // NREP*5120 floats
#define ACC_FLOATS (GSUM_OFF + NREP*5120) // 82304 floats
#define OFF_W1T    (OFF_ACC + (size_t)ACC_FLOATS*4)     // 8 C-tiles x 1KB (w1 bf16, padded to 16 classes)

#define GLL(g,l) __builtin_amdgcn_global_load_lds((const __attribute__((address_space(1))) void*)(g), (__attribute__((address_space(3))) void*)(l), 16, 0, 0)

__device__ __forceinline__ unsigned short f2b(float f){
  unsigned u = __float_as_uint(f);
  u += 0x7FFFu + ((u >> 16) & 1u);
  return (unsigned short)(u >> 16);
}
__device__ __forceinline__ float b2f(unsigned short h){
  return __uint_as_float(((unsigned)h) << 16);
}
__device__ __forceinline__ unsigned pk2b(float f0, float f1){
  unsigned u0 = __float_as_uint(f0) + 0x8000u;
  unsigned u1 = __float_as_uint(f1) + 0x8000u;
  return __builtin_amdgcn_perm(u1, u0, 0x07060302u);
}
__device__ __forceinline__ float ald(const float* p){
  return __hip_atomic_load(p, __ATOMIC_RELAXED, __HIP_MEMORY_SCOPE_AGENT);
}

// ---- K0: setup — xcast (0..2047, 2 I-tiles each for 8 blocks/CU occupancy),
//      weight prep (2048..2383), zero (2384..2464), class counts (2465..2480)
__global__ __launch_bounds__(256) void k_setup(
    const float* __restrict__ x,   const float* __restrict__ fc0,
    const float* __restrict__ fc1, const float* __restrict__ w,
    const float* __restrict__ w1,  const int* __restrict__ y,
    unsigned short* __restrict__ xT,   unsigned short* __restrict__ fc0T,
    unsigned short* __restrict__ fc1T, unsigned short* __restrict__ wT,
    unsigned short* __restrict__ w1T,  float* __restrict__ accb)
{
  int blk = blockIdx.x, t = threadIdx.x;
  if (blk < 2048){
    // x-cast via LDS transpose: contiguous 2KB-row reads AND contiguous 1KB
    // tile writes. LDS [16][520] bf16 (pad 8 shorts kills bank aliasing).
    // 2048 blocks x 2 I-tiles -> 8 blocks/CU (Little's-law fix for HBM sat).
    __shared__ __align__(16) unsigned short xls[16*520];
    int wv = t >> 6, l = t & 63;
    #pragma unroll 1
    for (int it = 0; it < 2; ++it){
      int I = blk*2 + it;
      #pragma unroll
      for (int rr = 0; rr < 4; ++rr){
        int row = wv*4 + rr;
        const float* src = x + ((size_t)(I*16 + row))*FDIM + l*8;
        float4 v0 = *(const float4*)src;
        float4 v1 = *(const float4*)(src + 4);
        unsigned o[4];
        o[0] = pk2b(v0.x, v0.y); o[1] = pk2b(v0.z, v0.w);
        o[2] = pk2b(v1.x, v1.y); o[3] = pk2b(v1.z, v1.w);
        *(short8*)&xls[row*520 + l*8] = *(short8*)o;
      }
      __syncthreads();
      #pragma unroll
      for (int cc = 0; cc < 4; ++cc){
        int C = cc*4 + wv;
        short8 v = *(const short8*)&xls[(l & 15)*520 + C*32 + (l >> 4)*8];
        *(short8*)&xT[(((size_t)I*16 + C) << 9) + l*8] = v;
      }
      __syncthreads();
    }
    return;
  }
  if (blk < 2384){
    int i = (blk - 2048)*256 + t;
    float l1v = 0.f;
    if (i < 32768){                       // fc0 [k][512] -> tiled
      int n4 = i&15, m = (i>>4)&3, C = (i>>6)&15, J = i>>10;
      int n = J*16+n4, k8 = C*4+m;
      unsigned short o[8];
      #pragma unroll
      for (int j=0;j<8;++j){ float v = fc0[(size_t)(k8*8+j)*512 + n]; o[j]=f2b(v); l1v += fabsf(v); }
      *(short8*)&fc0T[(size_t)(J*16+C)*512 + (i&63)*8] = *(short8*)o;
    } else if (i < 65536){                // fc1
      int j0 = i - 32768;
      int n4 = j0&15, m = (j0>>4)&3, C = (j0>>6)&15, J = j0>>10;
      int n = J*16+n4, k8 = C*4+m;
      unsigned short o[8];
      #pragma unroll
      for (int j=0;j<8;++j){ float v = fc1[(size_t)(k8*8+j)*512 + n]; o[j]=f2b(v); l1v += fabsf(v); }
      *(short8*)&fc1T[(size_t)(J*16+C)*512 + (j0&63)*8] = *(short8*)o;
    } else if (i < 81920){                // w [k][256]
      int j0 = i - 65536;
      int n4 = j0&15, m = (j0>>4)&3, C = (j0>>6)&15, J = j0>>10;
      int n = J*16+n4, k8 = C*4+m;
      unsigned short o[8];
      #pragma unroll
      for (int j=0;j<8;++j){ float v = w[(size_t)(k8*8+j)*256 + n]; o[j]=f2b(v); l1v += fabsf(v); }
      *(short8*)&wT[(size_t)(J*16+C)*512 + (j0&63)*8] = *(short8*)o;
    } else if (i < 86016){                // w1 -> B-fragment tiles (16 classes padded), + L1
      int j0 = i - 81920;                 // 0..4095, one bf16 each
      int C = j0 >> 9, l = (j0 >> 3) & 63, e = j0 & 7;
      int n = l & 15, k = C*32 + (l>>4)*8 + e;
      float v = (n < NC) ? w1[k*NC + n] : 0.f;
      w1T[C*512 + l*8 + e] = f2b(v);
      if (n < NC) l1v = fabsf(v);
    }
    for (int off = 32; off; off >>= 1) l1v += __shfl_down(l1v, off);
    if ((t & 63) == 0 && l1v != 0.f)
      atomicAdd(&accb[SCAL_L1 + (blk & (NREP-1))], l1v);
    return;
  }
  if (blk < 2465){
    int base = (blk - 2384)*1024;
    #pragma unroll
    for (int j=0;j<4;++j){
      int idx = base + j*256 + t;
      // exclude CNT region [CNT_OFF, CNT_OFF+256): fully written by cnt blocks
      if (idx < ACC_FLOATS && (idx < CNT_OFF || idx >= CNT_OFF + NREP*16))
        accb[idx] = 0.f;
    }
    return;
  }
  {
    // class counts: 16 blocks, 4096 labels each, private gcnt slot
    __shared__ float cntS[16];
    int b = blk - 2465;
    if (t < 16) cntS[t] = 0.f;
    __syncthreads();
    int base = b*4096;
    for (int i = t; i < 4096; i += 256) atomicAdd(&cntS[y[base+i]], 1.f);
    __syncthreads();
    if (t < 16) accb[CNT_OFF + b*16 + t] = cntS[t];
  }
}

// ---------------------------------------------------------------------------
// 8-phase fine-interleaved K-loop (round-3 verified). Block = 256 rows x
// (128 cols x 2 matrices); 8 waves; BK=64; double-buffered 128KB LDS
// (per buffer: A 32KB @0, B0 16KB @32K, B1 16KB @48K).
// ---------------------------------------------------------------------------

#define BARRIER() __builtin_amdgcn_s_barrier()
#define LGKM0() do{ asm volatile("s_waitcnt lgkmcnt(0)" ::: "memory"); \
                    __builtin_amdgcn_sched_barrier(0); }while(0)

#define RA(AB, C) do{                                                         \
  _Pragma("unroll") for (int m_=0;m_<8;++m_)                                  \
    a[m_] = *(const short8*)((AB) + (((wr*8+m_)*2 + (C))<<10) + lane*16);     \
}while(0)

#define RB(AB, MAT, C) do{                                                    \
  _Pragma("unroll") for (int n_=0;n_<2;++n_)                                  \
    bb[n_] = *(const short8*)((AB) + 32768 + (MAT)*16384 +                    \
                              (((wc*2+n_)*2 + (C))<<10) + lane*16);           \
}while(0)

#define MM16(ACC) do{                                                         \
  __builtin_amdgcn_s_setprio(1);                                              \
  _Pragma("unroll") for (int n_=0;n_<2;++n_)                                  \
  _Pragma("unroll") for (int m_=0;m_<8;++m_)                                  \
    ACC[m_][n_] = __builtin_amdgcn_mfma_f32_16x16x32_bf16(a[m_], bb[n_], ACC[m_][n_], 0,0,0); \
  __builtin_amdgcn_s_setprio(0);                                              \
}while(0)

#define SA(KT, C) do{                                                         \
  char* d_ = ldsd + (((KT)&1) ? 65536 : 0);                                   \
  _Pragma("unroll") for (int r_=0;r_<2;++r_){                                 \
    int I_ = wv + r_*8;                                                       \
    GLL(xb + (((size_t)((rowblk*16 + I_)*16 + (KT)*2 + (C))) << 10) + lane*16,\
        d_ + ((I_*2 + (C)) << 10) + lane*16);                                 \
  } }while(0)

#define SB(KT, C) do{                                                         \
  char* d_ = ldsd + (((KT)&1) ? 65536 : 0) + 32768;                           \
  GLL(b0b + (((size_t)((colblk*8 + wv)*16 + (KT)*2 + (C))) << 10) + lane*16,  \
      d_ + ((wv*2 + (C)) << 10) + lane*16);                                   \
  GLL(b1b + (((size_t)((colblk*8 + wv)*16 + (KT)*2 + (C))) << 10) + lane*16,  \
      d_ + 16384 + ((wv*2 + (C)) << 10) + lane*16);                           \
}while(0)

#define KLOOP() do{                                                           \
  SA(0,0); SB(0,0); SA(0,1); SB(0,1); SA(1,0); SB(1,0); SA(1,1);              \
  asm volatile("s_waitcnt vmcnt(6)" ::: "memory");                            \
  __builtin_amdgcn_sched_barrier(0);                                          \
  BARRIER();                                                                  \
  _Pragma("unroll")                                                           \
  for (int i = 0; i < 4; ++i){                                                \
    int kt0 = 2*i, kt1 = 2*i+1;                                               \
    char* Ab0 = ldsd + ((kt0 & 1) ? 65536 : 0);                               \
    char* Ab1 = ldsd + ((kt1 & 1) ? 65536 : 0);                               \
    RA(Ab0, 0); RB(Ab0, 0, 0);                                                \
    SB(kt1, 1);                                                               \
    BARRIER(); LGKM0(); MM16(acc1);                                           \
    BARRIER();                                                                \
    RB(Ab0, 1, 0);                                                            \
    if (i < 3) SA(kt0+2, 0);                                                  \
    BARRIER(); LGKM0(); MM16(acc2);                                           \
    BARRIER();                                                                \
    RA(Ab0, 1); RB(Ab0, 0, 1);                                                \
    if (i < 3) SB(kt0+2, 0);                                                  \
    BARRIER(); LGKM0(); MM16(acc1);                                           \
    BARRIER();                                                                \
    RB(Ab0, 1, 1);                                                            \
    if (i < 3) SA(kt0+2, 1);                                                  \
    BARRIER(); LGKM0(); MM16(acc2);                                           \
    if (i < 3) { asm volatile("s_waitcnt vmcnt(6)" ::: "memory"); }           \
    else       { asm volatile("s_waitcnt vmcnt(0)" ::: "memory"); }           \
    __builtin_amdgcn_sched_barrier(0);                                        \
    BARRIER();                                                                \
    RA(Ab1, 0); RB(Ab1, 0, 0);                                                \
    if (i < 3) SB(kt0+2, 1);                                                  \
    BARRIER(); LGKM0(); MM16(acc1);                                           \
    BARRIER();                                                                \
    RB(Ab1, 1, 0);                                                            \
    if (i < 3) SA(kt1+2, 0);                                                  \
    BARRIER(); LGKM0(); MM16(acc2);                                           \
    BARRIER();                                                                \
    RA(Ab1, 1); RB(Ab1, 0, 1);                                                \
    if (i < 3) SB(kt1+2, 0);                                                  \
    BARRIER(); LGKM0(); MM16(acc1);                                           \
    BARRIER();                                                                \
    RB(Ab1, 1, 1);                                                            \
    if (i < 3) SA(kt1+2, 1);                                                  \
    BARRIER(); LGKM0(); MM16(acc2);                                           \
    if (i < 3) { asm volatile("s_waitcnt vmcnt(6)" ::: "memory");             \
                 __builtin_amdgcn_sched_barrier(0); }                         \
    BARRIER();                                                                \
  }                                                                           \
}while(0)

// K1: dual GEMM x@fc0, x@fc1 + gated residual + register-based class-sum
// (masked-add in VGPRs + shfl quad-reduce + LDS combine + 1280 global atomics;
// NO LDS atomics — that was round-4's failure mode).
__global__ __launch_bounds__(512, 2) void k_gemm12(
    const unsigned short* __restrict__ xT,
    const unsigned short* __restrict__ fc0T,
    const unsigned short* __restrict__ fc1T,
    const int* __restrict__ y,
    unsigned short* __restrict__ x4T,
    float* __restrict__ accb)
{
  extern __shared__ __align__(16) char ldsd[];   // 131072 dynamic
  float* scal = accb;
  float* gsum = accb + GSUM_OFF;

  int blk = blockIdx.x;
  int wg = (blk & 7)*128 + (blk >> 3);           // bijective XCD chunking (1024%8==0)
  int rowblk = wg >> 2;                          // 0..255 (256 rows each)
  int colblk = wg & 3;                           // 0..3   (128 cols each)

  int t = threadIdx.x;
  int wv = t >> 6, lane = t & 63, ln = lane & 15, quad = lane >> 4;
  int wr = wv >> 2, wc = wv & 3;                 // 2 x 4 wave grid

  const char* xb  = (const char*)xT;
  const char* b0b = (const char*)fc0T;
  const char* b1b = (const char*)fc1T;

  const f32x4 zv = {0.f,0.f,0.f,0.f};
  f32x4 acc1[8][2], acc2[8][2];
  #pragma unroll
  for (int m=0;m<8;++m){ acc1[m][0]=zv; acc1[m][1]=zv; acc2[m][0]=zv; acc2[m][1]=zv; }

  short8 a[8], bb[2];

  KLOOP();

  // ---- epilogue: residual x into buf0 region, x4 bf16 into buf1 region
  {
    int Cres = colblk*4 + wc;
    #pragma unroll
    for (int i = 0; i < 8; ++i){
      GLL(xb + (((size_t)((rowblk*16 + wr*8 + i)*16 + Cres)) << 10) + lane*16,
          ldsd + ((wv*8 + i) << 10) + lane*16);
    }
    asm volatile("s_waitcnt vmcnt(0)" ::: "memory");
  }
  __syncthreads();

  unsigned short* resU = (unsigned short*)ldsd;
  unsigned short* x4U  = (unsigned short*)(ldsd + 65536);
  float sumsq = 0.f;
  #pragma unroll
  for (int m = 0; m < 8; ++m){
    #pragma unroll
    for (int n = 0; n < 2; ++n){
      #pragma unroll
      for (int r = 0; r < 4; ++r){
        int slot = (quad*4 + r) | ((n*2 + (ln>>3)) << 4);
        int idx = ((wv*8 + m) << 9) + slot*8 + (ln & 7);
        float xv  = b2f(resU[idx]);
        float x1v = acc1[m][n][r];
        float x2v = fmaxf(acc2[m][n][r], 0.f);
        float gate = 1.f + 1.f/(1.f + __expf(-x1v));
        float x4v = fmaf(gate, x2v, xv);
        unsigned short ub = f2b(x4v);
        float fq = b2f(ub);
        sumsq = fmaf(fq, fq, sumsq);
        x4U[idx] = ub;
        acc1[m][n][r] = fq;               // keep quantized value for class-sum
      }
    }
  }
  for (int off = 32; off; off >>= 1) sumsq += __shfl_down(sumsq, off);
  __syncthreads();                         // all res reads + x4 writes done; resU dead

  // ---- fused class-sum: per-thread masked-add over its 32 rows x 2 cols.
  // Thread value (m,n,r): row_local = wr*128 + m*16 + quad*4 + r,
  //                       col_local = wc*32 + n*16 + ln.
  float cs[NC][2];
  #pragma unroll
  for (int c=0;c<NC;++c){ cs[c][0]=0.f; cs[c][1]=0.f; }
  {
    const int* yrow = y + rowblk*256 + wr*128;
    #pragma unroll
    for (int m = 0; m < 8; ++m){
      int yv[4];
      #pragma unroll
      for (int r = 0; r < 4; ++r) yv[r] = yrow[m*16 + quad*4 + r];
      #pragma unroll
      for (int r = 0; r < 4; ++r){
        float v0 = acc1[m][0][r], v1 = acc1[m][1][r];
        #pragma unroll
        for (int c = 0; c < NC; ++c){
          bool msk = (yv[r] == c);
          cs[c][0] += msk ? v0 : 0.f;
          cs[c][1] += msk ? v1 : 0.f;
        }
      }
    }
  }
  // reduce across quad (lanes sharing ln): offsets 16, 32
  #pragma unroll
  for (int c = 0; c < NC; ++c)
    #pragma unroll
    for (int n = 0; n < 2; ++n){
      cs[c][n] += __shfl_xor(cs[c][n], 16);
      cs[c][n] += __shfl_xor(cs[c][n], 32);
    }

  float* red = (float*)ldsd;               // 32B, dead resU region
  float* ct  = (float*)(ldsd + 4096);      // [8 waves][NC][2][16] = 10KB
  if (lane == 0) red[wv] = sumsq;
  if (lane < 16){
    #pragma unroll
    for (int c = 0; c < NC; ++c)
      #pragma unroll
      for (int n = 0; n < 2; ++n)
        ct[((wv*NC + c)*2 + n)*16 + ln] = cs[c][n];
  }
  __syncthreads();
  if (t == 0){
    float s = 0.f;
    #pragma unroll
    for (int i=0;i<8;++i) s += red[i];
    atomicAdd(&scal[SCAL_SUMSQ + (blk & (NREP-1))], s);
  }
  // copy x4 LDS -> global (16B stores)
  #pragma unroll
  for (int r = 0; r < 2; ++r){
    int o = r*512 + t;
    int tile = o >> 6, off16 = o & 63;
    int wvp = tile >> 3, i = tile & 7;
    size_t Ig = (size_t)rowblk*16 + (wvp>>2)*8 + i;
    int Cg = colblk*4 + (wvp & 3);
    *(short8*)&x4T[((Ig*16 + Cg) << 9) + off16*8] =
      *(const short8*)&x4U[(tile << 9) + off16*8];
  }
  // flush class sums: combine wr=0/1 waves, one atomic per (class, col)
  for (int i = t; i < NC*128; i += 512){
    int c = i >> 7, col = i & 127;
    int wcx = col >> 5, nx = (col >> 4) & 1, lnx = col & 15;
    float v = ct[((wcx*NC + c)*2 + nx)*16 + lnx]
            + ct[(((4+wcx)*NC + c)*2 + nx)*16 + lnx];
    atomicAdd(&gsum[(size_t)(blk & (NREP-1))*5120 + c*512 + colblk*128 + col], v);
  }
}

// K2: h = relu(x4 @ w); logits = h @ w1; CE/argmax/acc; LAST block finalizes.
__global__ __launch_bounds__(512, 2) void k_gemm3_head(
    const unsigned short* __restrict__ x4T,
    const unsigned short* __restrict__ wT,
    const unsigned short* __restrict__ w1T,
    const int* __restrict__ y,
    float* __restrict__ accb,
    float* __restrict__ out)
{
  extern __shared__ __align__(16) char ldsd[];   // 131072 dynamic
  __shared__ float redc[8], reda[8];
  __shared__ int lastB;

  float* scal = accb;

  int blk = blockIdx.x;
  int rowblk = blk;                              // 256 rows each
  const int colblk = 0;

  int t = threadIdx.x;
  int wv = t >> 6, lane = t & 63, ln = lane & 15, quad = lane >> 4;
  int wr = wv >> 2, wc = wv & 3;
  int rep = (blk ^ (blk >> 4)) & (NREP-1);

  const char* xb  = (const char*)x4T;
  const char* b0b = (const char*)wT;                       // w cols 0..127 (J 0..7)
  const char* b1b = (const char*)wT + (size_t)128*1024;    // w cols 128..255 (J 8..15)

  const f32x4 zv = {0.f,0.f,0.f,0.f};
  f32x4 acc1[8][2], acc2[8][2];
  #pragma unroll
  for (int m=0;m<8;++m){ acc1[m][0]=zv; acc1[m][1]=zv; acc2[m][0]=zv; acc2[m][1]=zv; }

  short8 a[8], bb[2];

  KLOOP();

  // w1 B-fragments from global (8KB, L2-resident)
  short8 bw1[8];
  #pragma unroll
  for (int Ck = 0; Ck < 8; ++Ck)
    bw1[Ck] = *(const short8*)&w1T[Ck*512 + lane*8];

  // h = relu(acc) fragment-tiled into the (dead) full 128KB LDS
  unsigned short* transH = (unsigned short*)ldsd;
  #pragma unroll
  for (int m = 0; m < 8; ++m){
    #pragma unroll
    for (int n = 0; n < 2; ++n){
      #pragma unroll
      for (int r = 0; r < 4; ++r){
        int slot = (quad*4 + r) | ((n*2 + (ln>>3)) << 4);
        int e = ln & 7;
        int IhA = wr*8 + m;
        transH[((IhA*8 + wc)     << 9) + slot*8 + e] = f2b(fmaxf(acc1[m][n][r], 0.f));
        transH[((IhA*8 + 4 + wc) << 9) + slot*8 + e] = f2b(fmaxf(acc2[m][n][r], 0.f));
      }
    }
  }
  __syncthreads();

  // logits: each wave handles row-tiles Ih = wv*2 + {0,1}
  f32x4 alog[2] = {zv, zv};
  #pragma unroll
  for (int ih = 0; ih < 2; ++ih){
    int Ih = wv*2 + ih;
    #pragma unroll
    for (int Ck = 0; Ck < 8; ++Ck){
      short8 af = *(const short8*)&transH[((Ih*8 + Ck) << 9) + lane*8];
      alog[ih] = __builtin_amdgcn_mfma_f32_16x16x32_bf16(af, bw1[Ck], alog[ih], 0,0,0);
    }
  }

  // CE/argmax: row = blk*256 + Ih*16 + quad*4 + r, class = ln
  float ce_l = 0.f, acc_l = 0.f;
  #pragma unroll
  for (int ih = 0; ih < 2; ++ih){
    #pragma unroll
    for (int r = 0; r < 4; ++r){
      int grow = blk*256 + (wv*2 + ih)*16 + quad*4 + r;
      int yv = y[grow];
      float lg = (ln < NC) ? alog[ih][r] : -1e30f;
      float m = lg; int mi = ln;
      #pragma unroll
      for (int mk = 1; mk < 16; mk <<= 1){
        float om = __shfl_xor(m, mk); int oi = __shfl_xor(mi, mk);
        if (om > m || (om == m && oi < mi)){ m = om; mi = oi; }
      }
      float e  = (ln < NC) ? __expf(lg - m) : 0.f;
      float sy = (ln == yv) ? lg : 0.f;
      #pragma unroll
      for (int mk = 1; mk < 16; mk <<= 1){ e += __shfl_xor(e, mk); sy += __shfl_xor(sy, mk); }
      float lse = m + __logf(e);
      if (ln == 0){ ce_l += (lse - sy); acc_l += (mi == yv) ? 1.f : 0.f; }
    }
  }
  ce_l  += __shfl_down(ce_l, 16);  acc_l += __shfl_down(acc_l, 16);
  ce_l  += __shfl_down(ce_l, 32);  acc_l += __shfl_down(acc_l, 32);
  if (lane == 0){ redc[wv] = ce_l; reda[wv] = acc_l; }
  __syncthreads();
  if (t == 0){
    float c = 0.f, aa = 0.f;
    #pragma unroll
    for (int i=0;i<8;++i){ c += redc[i]; aa += reda[i]; }
    atomicAdd(&scal[SCAL_CE  + rep], c);
    atomicAdd(&scal[SCAL_ACC + rep], aa);
    __threadfence();
    int prev = atomicAdd((int*)(scal + SCAL_CTR), 1);
    lastB = (prev == (int)gridDim.x - 1);
  }
  __syncthreads();
  if (!lastB) return;

  // ---- merged k_final: last block reduces gsum/gcnt/scal -> out
  {
    const float* gsum = accb + GSUM_OFF;
    const float* gcnt = accb + CNT_OFF;
    float contrib = 0.f;
    for (int idx = t; idx < 5120; idx += 512){
      float S = 0.f;
      #pragma unroll
      for (int r = 0; r < NREP; ++r) S += ald(&gsum[(size_t)r*5120 + idx]);
      int c = idx >> 9;
      float cnt = 0.f;
      #pragma unroll
      for (int r = 0; r < NREP; ++r) cnt += ald(&gcnt[r*16 + c]);
      contrib += S*S / fmaxf(cnt, 1.f);
    }
    for (int off = 32; off; off >>= 1) contrib += __shfl_down(contrib, off);
    __syncthreads();                  // redc reusable
    if (lane == 0) redc[wv] = contrib;
    __syncthreads();
    if (t == 0){
      float var2 = 0.f;
      #pragma unroll
      for (int i=0;i<8;++i) var2 += redc[i];
      float sumsq=0.f, ce=0.f, accv=0.f, l1=0.f;
      for (int r=0;r<NREP;++r){
        sumsq += ald(&scal[SCAL_SUMSQ+r]);
        ce    += ald(&scal[SCAL_CE+r]);
        accv  += ald(&scal[SCAL_ACC+r]);
        l1    += ald(&scal[SCAL_L1+r]);
      }
      float var_loss = sumsq - var2;
      out[0] = ce/(float)BATCH + 1e-4f*l1 + 1e-3f*var_loss;
      out[1] = accv/(float)BATCH;
    }
  }
}

extern "C" void kernel_launch(void* const* d_in, const int* in_sizes, int n_in,
                              void* d_out, int out_size, void* d_ws, size_t ws_size,
                              hipStream_t stream){
  (void)in_sizes; (void)n_in; (void)out_size; (void)ws_size;
  const float* x   = (const float*)d_in[0];
  const int*   y   = (const int*)d_in[1];
  const float* fc0 = (const float*)d_in[2];
  const float* fc1 = (const float*)d_in[3];
  const float* w   = (const float*)d_in[4];
  const float* w1  = (const float*)d_in[5];
  char* ws = (char*)d_ws;
  unsigned short* fc0T = (unsigned short*)(ws + OFF_FC0T);
  unsigned short* fc1T = (unsigned short*)(ws + OFF_FC1T);
  unsigned short* wT   = (unsigned short*)(ws + OFF_WT);
  unsigned short* xT   = (unsigned short*)(ws + OFF_XT);
  unsigned short* x4T  = (unsigned short*)(ws + OFF_X4T);
  unsigned short* w1T  = (unsigned short*)(ws + OFF_W1T);
  float* accb = (float*)(ws + OFF_ACC);

  static bool once = [](){
    hipFuncSetAttribute((const void*)k_gemm12,
                        hipFuncAttributeMaxDynamicSharedMemorySize, 131072);
    hipFuncSetAttribute((const void*)k_gemm3_head,
                        hipFuncAttributeMaxDynamicSharedMemorySize, 131072);
    return true;
  }();
  (void)once;

  k_setup<<<2481, 256, 0, stream>>>(x, fc0, fc1, w, w1, y, xT, fc0T, fc1T, wT, w1T, accb);
  k_gemm12<<<1024, 512, 131072, stream>>>(xT, fc0T, fc1T, y, x4T, accb);
  k_gemm3_head<<<256, 512, 131072, stream>>>(x4T, wT, w1T, y, accb, (float*)d_out);
}